// Round 11
// baseline (231.491 us; speedup 1.0000x reference)
//
#include <hip/hip_runtime.h>
#include <hip/hip_fp16.h>
#include <math.h>

#define NPTS 262144
#define PLANE_ELEMS 16777216u   // 256*256*256

typedef __attribute__((ext_vector_type(4))) float f4;
typedef __attribute__((ext_vector_type(4))) unsigned int u4;

// ws layout (bytes):
//   [0, 96 MB)        : fp16 transposed planes (3 x 32 MB), layout [hw][c=256]
//   +12.58 MB         : sortedC float4[3][NPTS] (gx,gy,ax,bits(n)) pre-swizzled
//   +25.17 MB         : partial fp16[3][NPTS][16]
//   +0.75 MB          : hist unsigned[3][65536]
#define OFF_SORTED   (3ull * PLANE_ELEMS * 2ull)
#define OFF_PARTIAL  (OFF_SORTED + (size_t)3 * NPTS * 16)
#define OFF_HIST     (OFF_PARTIAL + (size_t)3 * NPTS * 16 * 2)
#define WS_NEED      (OFF_HIST + (size_t)3 * 65536 * 4)

__device__ __forceinline__ void plane_xy(int p, float c0, float c1, float c2,
                                         float& gx, float& gy, float& ax) {
  if (p == 0)      { gx = c1; gy = c2; ax = c0; }
  else if (p == 1) { gx = c0; gy = c2; ax = c1; }
  else             { gx = c0; gy = c1; ax = c2; }
}

__device__ __forceinline__ int cell_of(float g) {
  float i = (g + 1.f) * 0.5f * 255.f;
  int x0 = (int)floorf(i);
  return x0 < 0 ? 0 : (x0 > 255 ? 255 : x0);
}

// ---------------------------------------------------------------------------
// Transpose + convert: (C, H*W) fp32 -> (H*W, C) fp16.  [R10 verified:
// 4 tiles/block register ping-pong pipeline, nontemporal reads, 18 KB LDS,
// R7 swizzle. At ~5 TB/s mixed R/W this is at its roofline.]
// grid (128, 4, 3), block 256.
// ---------------------------------------------------------------------------
__device__ __forceinline__ void trans_load(const float* __restrict__ src,
                                           unsigned c0, unsigned hw0, int tid,
                                           f4 (&va)[4], f4 (&vb)[4]) {
#pragma unroll
  for (int j = 0; j < 4; ++j) {
    int idx = j * 256 + tid;  // 0..1023
    int rp = idx >> 5;        // 0..31 : c-pair index
    int q = idx & 31;         // 0..31 : f4 column (hw = 4q..4q+3)
    const f4* base = (const f4*)(src + (size_t)(c0 + 2 * rp) * 65536u + hw0 + 4 * q);
    va[j] = __builtin_nontemporal_load(base);
    vb[j] = __builtin_nontemporal_load(base + 16384);  // +65536 floats
  }
}

__device__ __forceinline__ void trans_proc(unsigned* tile, __half* dst,
                                           unsigned c0, unsigned hw0, int tid,
                                           f4 (&va)[4], f4 (&vb)[4]) {
#pragma unroll
  for (int j = 0; j < 4; ++j) {
    int idx = j * 256 + tid;
    int rp = idx >> 5;
    int q = idx & 31;
#pragma unroll
    for (int k = 0; k < 4; ++k) {
      int hw = 4 * q + k;
      __half2 h = __floats2half2_rn(va[j][k], vb[j][k]);
      tile[hw * 36 + (rp ^ (hw >> 3))] = *(unsigned*)&h;
    }
  }
  __syncthreads();
  int seg = tid & 7;
#pragma unroll
  for (int jj = 0; jj < 4; ++jj) {
    int hw = jj * 32 + (tid >> 3);
    int s = hw >> 3;          // wave-uniform
    u4 v = *(const u4*)(tile + hw * 36 + 4 * ((seg ^ (s >> 2)) & 7));
    u4 o;
    switch (s & 3) {          // wave-uniform unpermute of low2 of rp
      case 0: o = v; break;
      case 1: o = u4{v.y, v.x, v.w, v.z}; break;
      case 2: o = u4{v.z, v.w, v.x, v.y}; break;
      default: o = u4{v.w, v.z, v.y, v.x}; break;
    }
    *(u4*)((char*)dst + ((size_t)(hw0 + hw) * 256u + c0) * 2u + seg * 16u) = o;
  }
  __syncthreads();  // protect LDS reuse by next tile
}

__global__ __launch_bounds__(256) void PREFFFT_trans_k(
    const float* __restrict__ Pu, const float* __restrict__ Pv,
    const float* __restrict__ Pw, __half* __restrict__ dst0) {
  __shared__ unsigned tile[128 * 36];  // 18 KB
  const float* src = blockIdx.z == 0 ? Pu : (blockIdx.z == 1 ? Pv : Pw);
  __half* dst = dst0 + (size_t)blockIdx.z * PLANE_ELEMS;
  const unsigned hwbase = blockIdx.x * 512u;   // 4 tiles of 128 hw
  const unsigned c0 = blockIdx.y * 64u;
  const int tid = threadIdx.x;

  f4 vaA[4], vbA[4], vaB[4], vbB[4];
  trans_load(src, c0, hwbase, tid, vaA, vbA);
  trans_load(src, c0, hwbase + 128u, tid, vaB, vbB);
  trans_proc(tile, dst, c0, hwbase, tid, vaA, vbA);
  trans_load(src, c0, hwbase + 256u, tid, vaA, vbA);
  trans_proc(tile, dst, c0, hwbase + 128u, tid, vaB, vbB);
  trans_load(src, c0, hwbase + 384u, tid, vaB, vbB);
  trans_proc(tile, dst, c0, hwbase + 256u, tid, vaA, vbA);
  trans_proc(tile, dst, c0, hwbase + 384u, tid, vaB, vbB);
}

// ---------------------------------------------------------------------------
// Counting sort. R11: one thread per (point, plane) — grid (1024, 3) — so
// each thread has exactly ONE dependent atomic(+store) chain instead of 3
// sequential ones; 3x the independent waves hides the atomic/store latency.
// ---------------------------------------------------------------------------
__global__ __launch_bounds__(256) void PREFFFT_hist_k(
    const float* __restrict__ inputs, unsigned* __restrict__ hist) {
  int n = blockIdx.x * 256 + threadIdx.x;
  int p = blockIdx.y;
  float c0 = inputs[n * 3 + 0], c1 = inputs[n * 3 + 1], c2 = inputs[n * 3 + 2];
  float gx, gy, ax;
  plane_xy(p, c0, c1, c2, gx, gy, ax);
  int key = (cell_of(gy) << 8) | cell_of(gx);
  atomicAdd(&hist[p * 65536 + key], 1u);
}

__global__ __launch_bounds__(1024) void PREFFFT_scan_k(unsigned* __restrict__ hist) {
  __shared__ unsigned part[1024];
  unsigned* h = hist + (size_t)blockIdx.x * 65536;
  int t = threadIdx.x;
  unsigned s = 0;
#pragma unroll 8
  for (int i = 0; i < 64; ++i) s += h[t * 64 + i];
  part[t] = s;
  __syncthreads();
  for (int off = 1; off < 1024; off <<= 1) {
    unsigned v = (t >= off) ? part[t - off] : 0u;
    __syncthreads();
    part[t] += v;
    __syncthreads();
  }
  unsigned run = (t == 0) ? 0u : part[t - 1];
#pragma unroll 8
  for (int i = 0; i < 64; ++i) {
    unsigned c = h[t * 64 + i];
    h[t * 64 + i] = run;
    run += c;
  }
}

__global__ __launch_bounds__(256) void PREFFFT_scat_k(
    const float* __restrict__ inputs, unsigned* __restrict__ hist,
    float4* __restrict__ sortedC) {
  int n = blockIdx.x * 256 + threadIdx.x;
  int p = blockIdx.y;
  float c0 = inputs[n * 3 + 0], c1 = inputs[n * 3 + 1], c2 = inputs[n * 3 + 2];
  float gx, gy, ax;
  plane_xy(p, c0, c1, c2, gx, gy, ax);
  int key = (cell_of(gy) << 8) | cell_of(gx);
  unsigned pos = atomicAdd(&hist[p * 65536 + key], 1u);
  // store pre-swizzled plane coords: samp doesn't need plane_xy
  sortedC[(size_t)p * NPTS + pos] =
      make_float4(gx, gy, ax, __uint_as_float((unsigned)n));
}

// ---------------------------------------------------------------------------
// Sample pass: 8 lanes/point. Lane t owns re-ch2 {2t,2t+1} (plane ch t*16..+15)
// and im-ch2 {16+2t,16+2t+1} (plane ch 128+t*16..+15). Bilinear in packed
// fp16 (v_pk_fma_f16); Fourier dots in f32 with shared double-angle trig.
// Writes fp16 partials (4B/lane, 32B/point, by original index n).
// grid (NPTS/32, 3), block 256.  [R10 verified]
// ---------------------------------------------------------------------------
__global__ __launch_bounds__(256) void PREFFFT_samp_k(
    const float4* __restrict__ sortedC, const __half* __restrict__ T,
    __half* __restrict__ partial) {
  int p = blockIdx.y;
  int bx = blockIdx.x;                      // 0..8191
  int lbx = (bx & 7) * 1024 + (bx >> 3);    // XCD-contiguous chunks
  int slot = lbx * 32 + ((int)threadIdx.x >> 3);
  int t = threadIdx.x & 7;

  float4 sc = sortedC[(size_t)p * NPTS + slot];
  unsigned n = __float_as_uint(sc.w);
  float gx = sc.x, gy = sc.y, ax = sc.z;

  float ix = (gx + 1.f) * 0.5f * 255.f;
  float iy = (gy + 1.f) * 0.5f * 255.f;
  float x0f = floorf(ix), y0f = floorf(iy);
  float wx = ix - x0f, wy = iy - y0f;
  int x0 = (int)x0f; x0 = x0 < 0 ? 0 : (x0 > 255 ? 255 : x0);
  int y0 = (int)y0f; y0 = y0 < 0 ? 0 : (y0 > 255 ? 255 : y0);
  int x1 = x0 + 1 > 255 ? 255 : x0 + 1;
  int y1 = y0 + 1 > 255 ? 255 : y0 + 1;
  float w00 = (1.f - wx) * (1.f - wy);
  float w01 = wx * (1.f - wy);
  float w10 = (1.f - wx) * wy;
  float w11 = wx * wy;

  const __half* __restrict__ P = T + (size_t)p * PLANE_ELEMS;
  int r00 = (y0 * 256 + x0) * 256, r01 = (y0 * 256 + x1) * 256;
  int r10 = (y1 * 256 + x0) * 256, r11 = (y1 * 256 + x1) * 256;
  int ore = t * 16;         // re channels t*16..t*16+15
  int oim = 128 + t * 16;   // im channels

  // 16 x 16B loads (4 corners x {re_lo, re_hi, im_lo, im_hi})
  f4 a0 = *(const f4*)(P + r00 + ore),     a1 = *(const f4*)(P + r00 + ore + 8);
  f4 a2 = *(const f4*)(P + r00 + oim),     a3 = *(const f4*)(P + r00 + oim + 8);
  f4 b0 = *(const f4*)(P + r01 + ore),     b1 = *(const f4*)(P + r01 + ore + 8);
  f4 b2 = *(const f4*)(P + r01 + oim),     b3 = *(const f4*)(P + r01 + oim + 8);
  f4 c0v = *(const f4*)(P + r10 + ore),    c1v = *(const f4*)(P + r10 + ore + 8);
  f4 c2v = *(const f4*)(P + r10 + oim),    c3v = *(const f4*)(P + r10 + oim + 8);
  f4 d0 = *(const f4*)(P + r11 + ore),     d1 = *(const f4*)(P + r11 + ore + 8);
  f4 d2 = *(const f4*)(P + r11 + oim),     d3 = *(const f4*)(P + r11 + oim + 8);

  __half2 hw00 = __float2half2_rn(w00), hw01 = __float2half2_rn(w01);
  __half2 hw10 = __float2half2_rn(w10), hw11 = __float2half2_rn(w11);

  // bilinear blend in packed fp16: 16 h2 outputs (8 re, 8 im)
  __half2 bre[8], bim[8];
#pragma unroll
  for (int q = 0; q < 4; ++q) {
    __half2 v;
    v = __hmul2(((const __half2*)&a0)[q], hw00);
    v = __hfma2(((const __half2*)&b0)[q],  hw01, v);
    v = __hfma2(((const __half2*)&c0v)[q], hw10, v);
    bre[q] = __hfma2(((const __half2*)&d0)[q], hw11, v);

    v = __hmul2(((const __half2*)&a1)[q], hw00);
    v = __hfma2(((const __half2*)&b1)[q],  hw01, v);
    v = __hfma2(((const __half2*)&c1v)[q], hw10, v);
    bre[q + 4] = __hfma2(((const __half2*)&d1)[q], hw11, v);

    v = __hmul2(((const __half2*)&a2)[q], hw00);
    v = __hfma2(((const __half2*)&b2)[q],  hw01, v);
    v = __hfma2(((const __half2*)&c2v)[q], hw10, v);
    bim[q] = __hfma2(((const __half2*)&d2)[q], hw11, v);

    v = __hmul2(((const __half2*)&a3)[q], hw00);
    v = __hfma2(((const __half2*)&b3)[q],  hw01, v);
    v = __hfma2(((const __half2*)&c3v)[q], hw10, v);
    bim[q + 4] = __hfma2(((const __half2*)&d3)[q], hw11, v);
  }

  // unpack to f32: fre[0..7] = ch2=2t r=0..7; fre[8..15] = ch2=2t+1
  float fre[16], fim[16];
#pragma unroll
  for (int q = 0; q < 8; ++q) {
    float2 vr = __half22float2(bre[q]);
    float2 vi = __half22float2(bim[q]);
    fre[2 * q] = vr.x; fre[2 * q + 1] = vr.y;
    fim[2 * q] = vi.x; fim[2 * q + 1] = vi.y;
  }

  // Fourier: theta_r = theta1 * 2^(r-1); r=0 term cos=1 / sin=0.
  float cs = (ax + 1.f) * 0.5f * 255.f;
  float th = 6.283185307179586f * cs * (1.f / 256.f);
  float s, c;
  __sincosf(th, &s, &c);
  float aR0 = fre[0], aR1 = fre[8];
  float aI0 = 0.f,    aI1 = 0.f;
#pragma unroll
  for (int r = 1; r < 8; ++r) {
    aR0 += fre[r] * c;     aR1 += fre[8 + r] * c;
    aI0 += fim[r] * s;     aI1 += fim[8 + r] * s;
    if (r < 7) {
      float c2 = c + c;
      float cn = c2 * c - 1.f;   // cos(2a) = 2cos^2 - 1
      s = c2 * s;                // sin(2a) = 2 sin cos
      c = cn;
    }
  }

  *(__half2*)(partial + ((size_t)p * NPTS + n) * 16 + 2 * t) =
      __floats2half2_rn(aR0 - aI0, aR1 - aI1);
}

// ---------------------------------------------------------------------------
// Reduce: out = sum of 3 fp16 partials, f32 output. 8 outputs/thread.
// ---------------------------------------------------------------------------
__global__ __launch_bounds__(256) void PREFFFT_red_k(
    const __half* __restrict__ part, float* __restrict__ out) {
  size_t i = (size_t)blockIdx.x * 256 + threadIdx.x;  // < 524288
  const size_t PS = (size_t)NPTS * 16;
  union H8 { u4 v; __half2 h[4]; };
  H8 a, b, c;
  a.v = *(const u4*)(part + i * 8);
  b.v = *(const u4*)(part + PS + i * 8);
  c.v = *(const u4*)(part + 2 * PS + i * 8);
  f4 o0, o1;
#pragma unroll
  for (int k = 0; k < 4; ++k) {
    float2 fa = __half22float2(a.h[k]);
    float2 fb = __half22float2(b.h[k]);
    float2 fc = __half22float2(c.h[k]);
    float lo = fa.x + fb.x + fc.x;
    float hi = fa.y + fb.y + fc.y;
    if (k < 2) { o0[2 * k] = lo; o0[2 * k + 1] = hi; }
    else       { o1[2 * (k - 2)] = lo; o1[2 * (k - 2) + 1] = hi; }
  }
  ((f4*)out)[i * 2] = o0;
  ((f4*)out)[i * 2 + 1] = o1;
}

// ---------------------------------------------------------------------------
// Fallback (ws too small): original (C,H,W) fp32 direct, slow but correct.
// ---------------------------------------------------------------------------
__global__ __launch_bounds__(256) void PREFFFT_fallback_k(
    const float* __restrict__ inputs, const float* __restrict__ Tu,
    const float* __restrict__ Tv, const float* __restrict__ Tw,
    float* __restrict__ out) {
  int gtid = blockIdx.x * 256 + threadIdx.x;
  int n = gtid >> 5;
  int t = threadIdx.x & 31;
  const bool is_re = t < 16;
  float c0 = inputs[n * 3 + 0], c1 = inputs[n * 3 + 1], c2 = inputs[n * 3 + 2];
  const float* PL[3] = {Tu, Tv, Tw};
  float acc = 0.f;
#pragma unroll
  for (int p = 0; p < 3; ++p) {
    float gx, gy, ax;
    plane_xy(p, c0, c1, c2, gx, gy, ax);
    float ix = (gx + 1.f) * 0.5f * 255.f;
    float iy = (gy + 1.f) * 0.5f * 255.f;
    float x0f = floorf(ix), y0f = floorf(iy);
    float wx = ix - x0f, wy = iy - y0f;
    int x0 = (int)x0f; x0 = x0 < 0 ? 0 : (x0 > 255 ? 255 : x0);
    int y0 = (int)y0f; y0 = y0 < 0 ? 0 : (y0 > 255 ? 255 : y0);
    int x1 = x0 + 1 > 255 ? 255 : x0 + 1;
    int y1 = y0 + 1 > 255 ? 255 : y0 + 1;
    float w00 = (1.f - wx) * (1.f - wy), w01 = wx * (1.f - wy);
    float w10 = (1.f - wx) * wy, w11 = wx * wy;
    int i00 = y0 * 256 + x0, i01 = y0 * 256 + x1;
    int i10 = y1 * 256 + x0, i11 = y1 * 256 + x1;
    float b[8];
#pragma unroll
    for (int j = 0; j < 8; ++j) {
      const float* base = PL[p] + (size_t)(t * 8 + j) * 65536u;
      b[j] = w00 * base[i00] + w01 * base[i01] + w10 * base[i10] + w11 * base[i11];
    }
    float csv = (ax + 1.f) * 0.5f * 255.f;
    float theta1 = 6.283185307179586f * csv * (1.f / 256.f);
    float partial = is_re ? b[0] : 0.f;
#pragma unroll
    for (int r = 1; r < 8; ++r) {
      float thr = theta1 * (float)(1 << (r - 1));
      float s, c;
      __sincosf(thr, &s, &c);
      partial += b[r] * (is_re ? c : s);
    }
    float other = __shfl_xor(partial, 16);
    acc += partial - other;
  }
  if (is_re) out[n * 16 + t] = acc;
}

extern "C" void kernel_launch(void* const* d_in, const int* in_sizes, int n_in,
                              void* d_out, int out_size, void* d_ws, size_t ws_size,
                              hipStream_t stream) {
  const float* inputs = (const float*)d_in[0];
  const float* Pu = (const float*)d_in[1];
  const float* Pv = (const float*)d_in[2];
  const float* Pw = (const float*)d_in[3];
  float* out = (float*)d_out;

  if (ws_size >= WS_NEED) {
    char* ws = (char*)d_ws;
    __half*   T       = (__half*)ws;
    float4*   sortedC = (float4*)(ws + OFF_SORTED);
    __half*   partial = (__half*)(ws + OFF_PARTIAL);
    unsigned* hist    = (unsigned*)(ws + OFF_HIST);

    {
      dim3 tg(128, 4, 3);   // 4 pipelined 64c x 128hw tiles per block
      PREFFFT_trans_k<<<tg, 256, 0, stream>>>(Pu, Pv, Pw, T);
    }
    hipMemsetAsync(hist, 0, (size_t)3 * 65536 * 4, stream);
    {
      dim3 tg(NPTS / 256, 3);   // one thread per (point, plane)
      PREFFFT_hist_k<<<tg, 256, 0, stream>>>(inputs, hist);
    }
    PREFFFT_scan_k<<<3, 1024, 0, stream>>>(hist);
    {
      dim3 tg(NPTS / 256, 3);   // one thread per (point, plane)
      PREFFFT_scat_k<<<tg, 256, 0, stream>>>(inputs, hist, sortedC);
    }
    {
      dim3 tg(NPTS / 32, 3);
      PREFFFT_samp_k<<<tg, 256, 0, stream>>>(sortedC, T, partial);
    }
    PREFFFT_red_k<<<2048, 256, 0, stream>>>(partial, out);
  } else {
    PREFFFT_fallback_k<<<NPTS / 8, 256, 0, stream>>>(inputs, Pu, Pv, Pw, out);
  }
}

// Round 12
// 213.582 us; speedup vs baseline: 1.0839x; 1.0839x over previous
//
#include <hip/hip_runtime.h>
#include <hip/hip_fp16.h>
#include <math.h>

#define NPTS 262144
#define PLANE_ELEMS 16777216u   // 256*256*256

typedef __attribute__((ext_vector_type(4))) float f4;
typedef __attribute__((ext_vector_type(4))) unsigned int u4;

// ws layout (bytes):
//   [0, 96 MB)        : fp16 transposed planes (3 x 32 MB), layout [hw][c=256]
//   +3.1 MB           : idx u32[3][NPTS]  (sorted pos -> original n)
//   +25.17 MB         : partial fp16[3][NPTS][16]
//   +0.75 MB          : hist unsigned[3][65536]
#define OFF_IDX      (3ull * PLANE_ELEMS * 2ull)
#define OFF_PARTIAL  (OFF_IDX + (size_t)3 * NPTS * 4)
#define OFF_HIST     (OFF_PARTIAL + (size_t)3 * NPTS * 16 * 2)
#define WS_NEED      (OFF_HIST + (size_t)3 * 65536 * 4)

__device__ __forceinline__ void plane_xy(int p, float c0, float c1, float c2,
                                         float& gx, float& gy, float& ax) {
  if (p == 0)      { gx = c1; gy = c2; ax = c0; }
  else if (p == 1) { gx = c0; gy = c2; ax = c1; }
  else             { gx = c0; gy = c1; ax = c2; }
}

__device__ __forceinline__ int cell_of(float g) {
  float i = (g + 1.f) * 0.5f * 255.f;
  int x0 = (int)floorf(i);
  return x0 < 0 ? 0 : (x0 > 255 ? 255 : x0);
}

// ---------------------------------------------------------------------------
// Trans helpers (R10-verified): 64c x 128hw tiles, register ping-pong,
// nontemporal reads, swizzled LDS, b128 reads + 16B coalesced stores.
// ---------------------------------------------------------------------------
__device__ __forceinline__ void trans_load(const float* __restrict__ src,
                                           unsigned c0, unsigned hw0, int tid,
                                           f4 (&va)[4], f4 (&vb)[4]) {
#pragma unroll
  for (int j = 0; j < 4; ++j) {
    int idx = j * 256 + tid;  // 0..1023
    int rp = idx >> 5;        // 0..31 : c-pair index
    int q = idx & 31;         // 0..31 : f4 column (hw = 4q..4q+3)
    const f4* base = (const f4*)(src + (size_t)(c0 + 2 * rp) * 65536u + hw0 + 4 * q);
    va[j] = __builtin_nontemporal_load(base);
    vb[j] = __builtin_nontemporal_load(base + 16384);  // +65536 floats
  }
}

__device__ __forceinline__ void trans_proc(unsigned* tile, __half* dst,
                                           unsigned c0, unsigned hw0, int tid,
                                           f4 (&va)[4], f4 (&vb)[4]) {
#pragma unroll
  for (int j = 0; j < 4; ++j) {
    int idx = j * 256 + tid;
    int rp = idx >> 5;
    int q = idx & 31;
#pragma unroll
    for (int k = 0; k < 4; ++k) {
      int hw = 4 * q + k;
      __half2 h = __floats2half2_rn(va[j][k], vb[j][k]);
      tile[hw * 36 + (rp ^ (hw >> 3))] = *(unsigned*)&h;
    }
  }
  __syncthreads();
  int seg = tid & 7;
#pragma unroll
  for (int jj = 0; jj < 4; ++jj) {
    int hw = jj * 32 + (tid >> 3);
    int s = hw >> 3;          // wave-uniform
    u4 v = *(const u4*)(tile + hw * 36 + 4 * ((seg ^ (s >> 2)) & 7));
    u4 o;
    switch (s & 3) {          // wave-uniform unpermute of low2 of rp
      case 0: o = v; break;
      case 1: o = u4{v.y, v.x, v.w, v.z}; break;
      case 2: o = u4{v.z, v.w, v.x, v.y}; break;
      default: o = u4{v.w, v.z, v.y, v.x}; break;
    }
    *(u4*)((char*)dst + ((size_t)(hw0 + hw) * 256u + c0) * 2u + seg * 16u) = o;
  }
  __syncthreads();  // protect LDS reuse by next tile
}

// ---------------------------------------------------------------------------
// K1 fat kernel: blocks [0,1536) = transpose (trans work is plane-data-bound);
// blocks [1536,2304) = histogram (inputs + atomics, latency-bound) — the two
// are data-independent, so hist hides under trans in ONE dispatch.
// grid 2304, block 256. hist must see zeroed bins: memset runs before K1.
// ---------------------------------------------------------------------------
__global__ __launch_bounds__(256) void PREFFFT_fat1_k(
    const float* __restrict__ Pu, const float* __restrict__ Pv,
    const float* __restrict__ Pw, __half* __restrict__ dst0,
    const float* __restrict__ inputs, unsigned* __restrict__ hist) {
  __shared__ unsigned tile[128 * 36];  // 18 KB (trans blocks only)
  const int bx = blockIdx.x;
  const int tid = threadIdx.x;
  if (bx < 1536) {
    int bz = bx / 512;         // plane
    int rem = bx - bz * 512;
    int by = rem >> 7;         // c-block 0..3
    int bxx = rem & 127;       // hw quad 0..127
    const float* src = bz == 0 ? Pu : (bz == 1 ? Pv : Pw);
    __half* dst = dst0 + (size_t)bz * PLANE_ELEMS;
    const unsigned hwbase = bxx * 512u;
    const unsigned c0 = by * 64u;
    f4 vaA[4], vbA[4], vaB[4], vbB[4];
    trans_load(src, c0, hwbase, tid, vaA, vbA);
    trans_load(src, c0, hwbase + 128u, tid, vaB, vbB);
    trans_proc(tile, dst, c0, hwbase, tid, vaA, vbA);
    trans_load(src, c0, hwbase + 256u, tid, vaA, vbA);
    trans_proc(tile, dst, c0, hwbase + 128u, tid, vaB, vbB);
    trans_load(src, c0, hwbase + 384u, tid, vaB, vbB);
    trans_proc(tile, dst, c0, hwbase + 256u, tid, vaA, vbA);
    trans_proc(tile, dst, c0, hwbase + 384u, tid, vaB, vbB);
  } else {
    int hb = bx - 1536;        // 0..767
#pragma unroll
    for (int it = 0; it < 4; ++it) {
      int item = hb * 1024 + it * 256 + tid;   // < 786432
      int n = item & (NPTS - 1);
      int p = item >> 18;
      float c0 = inputs[n * 3 + 0], c1 = inputs[n * 3 + 1], c2 = inputs[n * 3 + 2];
      float gx, gy, ax;
      plane_xy(p, c0, c1, c2, gx, gy, ax);
      int key = (cell_of(gy) << 8) | cell_of(gx);
      atomicAdd(&hist[p * 65536 + key], 1u);
    }
  }
}

// ---------------------------------------------------------------------------
// Scan: exclusive prefix over 65536 bins; one block per plane.
// ---------------------------------------------------------------------------
__global__ __launch_bounds__(1024) void PREFFFT_scan_k(unsigned* __restrict__ hist) {
  __shared__ unsigned part[1024];
  unsigned* h = hist + (size_t)blockIdx.x * 65536;
  int t = threadIdx.x;
  unsigned s = 0;
#pragma unroll 8
  for (int i = 0; i < 64; ++i) s += h[t * 64 + i];
  part[t] = s;
  __syncthreads();
  for (int off = 1; off < 1024; off <<= 1) {
    unsigned v = (t >= off) ? part[t - off] : 0u;
    __syncthreads();
    part[t] += v;
    __syncthreads();
  }
  unsigned run = (t == 0) ? 0u : part[t - 1];
#pragma unroll 8
  for (int i = 0; i < 64; ++i) {
    unsigned c = h[t * 64 + i];
    h[t * 64 + i] = run;
    run += c;
  }
}

// ---------------------------------------------------------------------------
// Scatter: R12 — payload shrunk to 4B (original index only). The 16B
// coordinate payload was causing 4x partial-line write amplification
// (R10: WRITE_SIZE 50 MB on 12.6 MB of data). samp re-gathers coords.
// grid (1024, 3), block 256.
// ---------------------------------------------------------------------------
__global__ __launch_bounds__(256) void PREFFFT_scat_k(
    const float* __restrict__ inputs, unsigned* __restrict__ hist,
    unsigned* __restrict__ idx) {
  int n = blockIdx.x * 256 + threadIdx.x;
  int p = blockIdx.y;
  float c0 = inputs[n * 3 + 0], c1 = inputs[n * 3 + 1], c2 = inputs[n * 3 + 2];
  float gx, gy, ax;
  plane_xy(p, c0, c1, c2, gx, gy, ax);
  int key = (cell_of(gy) << 8) | cell_of(gx);
  unsigned pos = atomicAdd(&hist[p * 65536 + key], 1u);
  idx[(size_t)p * NPTS + pos] = (unsigned)n;
}

// ---------------------------------------------------------------------------
// Sample pass: 8 lanes/point, sorted order via idx; all 8 lanes share n so
// the inputs gather is one broadcast line (inputs is L2-resident, 3 MB).
// Lane t owns re-ch2 {2t,2t+1} and im-ch2 {16+2t,16+2t+1}; bilinear in packed
// fp16; Fourier in f32 with double-angle trig. fp16 partials by original n.
// grid (NPTS/32, 3), block 256.
// ---------------------------------------------------------------------------
__global__ __launch_bounds__(256) void PREFFFT_samp_k(
    const unsigned* __restrict__ idx, const float* __restrict__ inputs,
    const __half* __restrict__ T, __half* __restrict__ partial) {
  int p = blockIdx.y;
  int bx = blockIdx.x;                      // 0..8191
  int lbx = (bx & 7) * 1024 + (bx >> 3);    // XCD-contiguous chunks
  int slot = lbx * 32 + ((int)threadIdx.x >> 3);
  int t = threadIdx.x & 7;

  unsigned n = idx[(size_t)p * NPTS + slot];
  float c0 = inputs[n * 3 + 0], c1 = inputs[n * 3 + 1], c2 = inputs[n * 3 + 2];
  float gx, gy, ax;
  plane_xy(p, c0, c1, c2, gx, gy, ax);

  float ix = (gx + 1.f) * 0.5f * 255.f;
  float iy = (gy + 1.f) * 0.5f * 255.f;
  float x0f = floorf(ix), y0f = floorf(iy);
  float wx = ix - x0f, wy = iy - y0f;
  int x0 = (int)x0f; x0 = x0 < 0 ? 0 : (x0 > 255 ? 255 : x0);
  int y0 = (int)y0f; y0 = y0 < 0 ? 0 : (y0 > 255 ? 255 : y0);
  int x1 = x0 + 1 > 255 ? 255 : x0 + 1;
  int y1 = y0 + 1 > 255 ? 255 : y0 + 1;
  float w00 = (1.f - wx) * (1.f - wy);
  float w01 = wx * (1.f - wy);
  float w10 = (1.f - wx) * wy;
  float w11 = wx * wy;

  const __half* __restrict__ P = T + (size_t)p * PLANE_ELEMS;
  int r00 = (y0 * 256 + x0) * 256, r01 = (y0 * 256 + x1) * 256;
  int r10 = (y1 * 256 + x0) * 256, r11 = (y1 * 256 + x1) * 256;
  int ore = t * 16;         // re channels t*16..t*16+15
  int oim = 128 + t * 16;   // im channels

  // 16 x 16B loads (4 corners x {re_lo, re_hi, im_lo, im_hi})
  f4 a0 = *(const f4*)(P + r00 + ore),     a1 = *(const f4*)(P + r00 + ore + 8);
  f4 a2 = *(const f4*)(P + r00 + oim),     a3 = *(const f4*)(P + r00 + oim + 8);
  f4 b0 = *(const f4*)(P + r01 + ore),     b1 = *(const f4*)(P + r01 + ore + 8);
  f4 b2 = *(const f4*)(P + r01 + oim),     b3 = *(const f4*)(P + r01 + oim + 8);
  f4 c0v = *(const f4*)(P + r10 + ore),    c1v = *(const f4*)(P + r10 + ore + 8);
  f4 c2v = *(const f4*)(P + r10 + oim),    c3v = *(const f4*)(P + r10 + oim + 8);
  f4 d0 = *(const f4*)(P + r11 + ore),     d1 = *(const f4*)(P + r11 + ore + 8);
  f4 d2 = *(const f4*)(P + r11 + oim),     d3 = *(const f4*)(P + r11 + oim + 8);

  __half2 hw00 = __float2half2_rn(w00), hw01 = __float2half2_rn(w01);
  __half2 hw10 = __float2half2_rn(w10), hw11 = __float2half2_rn(w11);

  // bilinear blend in packed fp16: 16 h2 outputs (8 re, 8 im)
  __half2 bre[8], bim[8];
#pragma unroll
  for (int q = 0; q < 4; ++q) {
    __half2 v;
    v = __hmul2(((const __half2*)&a0)[q], hw00);
    v = __hfma2(((const __half2*)&b0)[q],  hw01, v);
    v = __hfma2(((const __half2*)&c0v)[q], hw10, v);
    bre[q] = __hfma2(((const __half2*)&d0)[q], hw11, v);

    v = __hmul2(((const __half2*)&a1)[q], hw00);
    v = __hfma2(((const __half2*)&b1)[q],  hw01, v);
    v = __hfma2(((const __half2*)&c1v)[q], hw10, v);
    bre[q + 4] = __hfma2(((const __half2*)&d1)[q], hw11, v);

    v = __hmul2(((const __half2*)&a2)[q], hw00);
    v = __hfma2(((const __half2*)&b2)[q],  hw01, v);
    v = __hfma2(((const __half2*)&c2v)[q], hw10, v);
    bim[q] = __hfma2(((const __half2*)&d2)[q], hw11, v);

    v = __hmul2(((const __half2*)&a3)[q], hw00);
    v = __hfma2(((const __half2*)&b3)[q],  hw01, v);
    v = __hfma2(((const __half2*)&c3v)[q], hw10, v);
    bim[q + 4] = __hfma2(((const __half2*)&d3)[q], hw11, v);
  }

  // unpack to f32: fre[0..7] = ch2=2t r=0..7; fre[8..15] = ch2=2t+1
  float fre[16], fim[16];
#pragma unroll
  for (int q = 0; q < 8; ++q) {
    float2 vr = __half22float2(bre[q]);
    float2 vi = __half22float2(bim[q]);
    fre[2 * q] = vr.x; fre[2 * q + 1] = vr.y;
    fim[2 * q] = vi.x; fim[2 * q + 1] = vi.y;
  }

  // Fourier: theta_r = theta1 * 2^(r-1); r=0 term cos=1 / sin=0.
  float cs = (ax + 1.f) * 0.5f * 255.f;
  float th = 6.283185307179586f * cs * (1.f / 256.f);
  float s, c;
  __sincosf(th, &s, &c);
  float aR0 = fre[0], aR1 = fre[8];
  float aI0 = 0.f,    aI1 = 0.f;
#pragma unroll
  for (int r = 1; r < 8; ++r) {
    aR0 += fre[r] * c;     aR1 += fre[8 + r] * c;
    aI0 += fim[r] * s;     aI1 += fim[8 + r] * s;
    if (r < 7) {
      float c2 = c + c;
      float cn = c2 * c - 1.f;   // cos(2a) = 2cos^2 - 1
      s = c2 * s;                // sin(2a) = 2 sin cos
      c = cn;
    }
  }

  *(__half2*)(partial + ((size_t)p * NPTS + n) * 16 + 2 * t) =
      __floats2half2_rn(aR0 - aI0, aR1 - aI1);
}

// ---------------------------------------------------------------------------
// Reduce: out = sum of 3 fp16 partials, f32 output. 8 outputs/thread.
// ---------------------------------------------------------------------------
__global__ __launch_bounds__(256) void PREFFFT_red_k(
    const __half* __restrict__ part, float* __restrict__ out) {
  size_t i = (size_t)blockIdx.x * 256 + threadIdx.x;  // < 524288
  const size_t PS = (size_t)NPTS * 16;
  union H8 { u4 v; __half2 h[4]; };
  H8 a, b, c;
  a.v = *(const u4*)(part + i * 8);
  b.v = *(const u4*)(part + PS + i * 8);
  c.v = *(const u4*)(part + 2 * PS + i * 8);
  f4 o0, o1;
#pragma unroll
  for (int k = 0; k < 4; ++k) {
    float2 fa = __half22float2(a.h[k]);
    float2 fb = __half22float2(b.h[k]);
    float2 fc = __half22float2(c.h[k]);
    float lo = fa.x + fb.x + fc.x;
    float hi = fa.y + fb.y + fc.y;
    if (k < 2) { o0[2 * k] = lo; o0[2 * k + 1] = hi; }
    else       { o1[2 * (k - 2)] = lo; o1[2 * (k - 2) + 1] = hi; }
  }
  ((f4*)out)[i * 2] = o0;
  ((f4*)out)[i * 2 + 1] = o1;
}

// ---------------------------------------------------------------------------
// Fallback (ws too small): original (C,H,W) fp32 direct, slow but correct.
// ---------------------------------------------------------------------------
__global__ __launch_bounds__(256) void PREFFFT_fallback_k(
    const float* __restrict__ inputs, const float* __restrict__ Tu,
    const float* __restrict__ Tv, const float* __restrict__ Tw,
    float* __restrict__ out) {
  int gtid = blockIdx.x * 256 + threadIdx.x;
  int n = gtid >> 5;
  int t = threadIdx.x & 31;
  const bool is_re = t < 16;
  float c0 = inputs[n * 3 + 0], c1 = inputs[n * 3 + 1], c2 = inputs[n * 3 + 2];
  const float* PL[3] = {Tu, Tv, Tw};
  float acc = 0.f;
#pragma unroll
  for (int p = 0; p < 3; ++p) {
    float gx, gy, ax;
    plane_xy(p, c0, c1, c2, gx, gy, ax);
    float ix = (gx + 1.f) * 0.5f * 255.f;
    float iy = (gy + 1.f) * 0.5f * 255.f;
    float x0f = floorf(ix), y0f = floorf(iy);
    float wx = ix - x0f, wy = iy - y0f;
    int x0 = (int)x0f; x0 = x0 < 0 ? 0 : (x0 > 255 ? 255 : x0);
    int y0 = (int)y0f; y0 = y0 < 0 ? 0 : (y0 > 255 ? 255 : y0);
    int x1 = x0 + 1 > 255 ? 255 : x0 + 1;
    int y1 = y0 + 1 > 255 ? 255 : y0 + 1;
    float w00 = (1.f - wx) * (1.f - wy), w01 = wx * (1.f - wy);
    float w10 = (1.f - wx) * wy, w11 = wx * wy;
    int i00 = y0 * 256 + x0, i01 = y0 * 256 + x1;
    int i10 = y1 * 256 + x0, i11 = y1 * 256 + x1;
    float b[8];
#pragma unroll
    for (int j = 0; j < 8; ++j) {
      const float* base = PL[p] + (size_t)(t * 8 + j) * 65536u;
      b[j] = w00 * base[i00] + w01 * base[i01] + w10 * base[i10] + w11 * base[i11];
    }
    float csv = (ax + 1.f) * 0.5f * 255.f;
    float theta1 = 6.283185307179586f * csv * (1.f / 256.f);
    float partial = is_re ? b[0] : 0.f;
#pragma unroll
    for (int r = 1; r < 8; ++r) {
      float thr = theta1 * (float)(1 << (r - 1));
      float s, c;
      __sincosf(thr, &s, &c);
      partial += b[r] * (is_re ? c : s);
    }
    float other = __shfl_xor(partial, 16);
    acc += partial - other;
  }
  if (is_re) out[n * 16 + t] = acc;
}

extern "C" void kernel_launch(void* const* d_in, const int* in_sizes, int n_in,
                              void* d_out, int out_size, void* d_ws, size_t ws_size,
                              hipStream_t stream) {
  const float* inputs = (const float*)d_in[0];
  const float* Pu = (const float*)d_in[1];
  const float* Pv = (const float*)d_in[2];
  const float* Pw = (const float*)d_in[3];
  float* out = (float*)d_out;

  if (ws_size >= WS_NEED) {
    char* ws = (char*)d_ws;
    __half*   T       = (__half*)ws;
    unsigned* idx     = (unsigned*)(ws + OFF_IDX);
    __half*   partial = (__half*)(ws + OFF_PARTIAL);
    unsigned* hist    = (unsigned*)(ws + OFF_HIST);

    hipMemsetAsync(hist, 0, (size_t)3 * 65536 * 4, stream);
    PREFFFT_fat1_k<<<2304, 256, 0, stream>>>(Pu, Pv, Pw, T, inputs, hist);
    PREFFFT_scan_k<<<3, 1024, 0, stream>>>(hist);
    {
      dim3 tg(NPTS / 256, 3);
      PREFFFT_scat_k<<<tg, 256, 0, stream>>>(inputs, hist, idx);
    }
    {
      dim3 tg(NPTS / 32, 3);
      PREFFFT_samp_k<<<tg, 256, 0, stream>>>(idx, inputs, T, partial);
    }
    PREFFFT_red_k<<<2048, 256, 0, stream>>>(partial, out);
  } else {
    PREFFFT_fallback_k<<<NPTS / 8, 256, 0, stream>>>(inputs, Pu, Pv, Pw, out);
  }
}

// Round 13
// 208.179 us; speedup vs baseline: 1.1120x; 1.0260x over previous
//
#include <hip/hip_runtime.h>
#include <hip/hip_fp16.h>
#include <math.h>

#define NPTS 262144
#define PLANE_ELEMS 16777216u   // 256*256*256

typedef __attribute__((ext_vector_type(4))) float f4;
typedef __attribute__((ext_vector_type(4))) unsigned int u4;

// ws layout (bytes):
//   [0, 96 MB)        : fp16 transposed planes (3 x 32 MB), layout [hw][c=256]
//   +3.1 MB           : idx u32[3][NPTS]  (sorted pos -> original n)
//   +25.17 MB         : partial fp16[3][NPTS][16]
//   +0.75 MB          : hist unsigned[3][65536]
#define OFF_IDX      (3ull * PLANE_ELEMS * 2ull)
#define OFF_PARTIAL  (OFF_IDX + (size_t)3 * NPTS * 4)
#define OFF_HIST     (OFF_PARTIAL + (size_t)3 * NPTS * 16 * 2)
#define WS_NEED      (OFF_HIST + (size_t)3 * 65536 * 4)

__device__ __forceinline__ void plane_xy(int p, float c0, float c1, float c2,
                                         float& gx, float& gy, float& ax) {
  if (p == 0)      { gx = c1; gy = c2; ax = c0; }
  else if (p == 1) { gx = c0; gy = c2; ax = c1; }
  else             { gx = c0; gy = c1; ax = c2; }
}

__device__ __forceinline__ int cell_of(float g) {
  float i = (g + 1.f) * 0.5f * 255.f;
  int x0 = (int)floorf(i);
  return x0 < 0 ? 0 : (x0 > 255 ? 255 : x0);
}

// ---------------------------------------------------------------------------
// Trans helpers (R10-verified).
// ---------------------------------------------------------------------------
__device__ __forceinline__ void trans_load(const float* __restrict__ src,
                                           unsigned c0, unsigned hw0, int tid,
                                           f4 (&va)[4], f4 (&vb)[4]) {
#pragma unroll
  for (int j = 0; j < 4; ++j) {
    int idx = j * 256 + tid;
    int rp = idx >> 5;
    int q = idx & 31;
    const f4* base = (const f4*)(src + (size_t)(c0 + 2 * rp) * 65536u + hw0 + 4 * q);
    va[j] = __builtin_nontemporal_load(base);
    vb[j] = __builtin_nontemporal_load(base + 16384);
  }
}

__device__ __forceinline__ void trans_proc(unsigned* tile, __half* dst,
                                           unsigned c0, unsigned hw0, int tid,
                                           f4 (&va)[4], f4 (&vb)[4]) {
#pragma unroll
  for (int j = 0; j < 4; ++j) {
    int idx = j * 256 + tid;
    int rp = idx >> 5;
    int q = idx & 31;
#pragma unroll
    for (int k = 0; k < 4; ++k) {
      int hw = 4 * q + k;
      __half2 h = __floats2half2_rn(va[j][k], vb[j][k]);
      tile[hw * 36 + (rp ^ (hw >> 3))] = *(unsigned*)&h;
    }
  }
  __syncthreads();
  int seg = tid & 7;
#pragma unroll
  for (int jj = 0; jj < 4; ++jj) {
    int hw = jj * 32 + (tid >> 3);
    int s = hw >> 3;
    u4 v = *(const u4*)(tile + hw * 36 + 4 * ((seg ^ (s >> 2)) & 7));
    u4 o;
    switch (s & 3) {
      case 0: o = v; break;
      case 1: o = u4{v.y, v.x, v.w, v.z}; break;
      case 2: o = u4{v.z, v.w, v.x, v.y}; break;
      default: o = u4{v.w, v.z, v.y, v.x}; break;
    }
    *(u4*)((char*)dst + ((size_t)(hw0 + hw) * 256u + c0) * 2u + seg * 16u) = o;
  }
  __syncthreads();
}

// ---------------------------------------------------------------------------
// Sample body (R12-verified): one (plane, sorted slot) by an 8-lane group.
// ---------------------------------------------------------------------------
__device__ __forceinline__ void samp_point(
    int p, int slot, int t, const unsigned* __restrict__ idx,
    const float* __restrict__ inputs, const __half* __restrict__ T,
    __half* __restrict__ partial) {
  unsigned n = idx[(size_t)p * NPTS + slot];
  float c0 = inputs[n * 3 + 0], c1 = inputs[n * 3 + 1], c2 = inputs[n * 3 + 2];
  float gx, gy, ax;
  plane_xy(p, c0, c1, c2, gx, gy, ax);

  float ix = (gx + 1.f) * 0.5f * 255.f;
  float iy = (gy + 1.f) * 0.5f * 255.f;
  float x0f = floorf(ix), y0f = floorf(iy);
  float wx = ix - x0f, wy = iy - y0f;
  int x0 = (int)x0f; x0 = x0 < 0 ? 0 : (x0 > 255 ? 255 : x0);
  int y0 = (int)y0f; y0 = y0 < 0 ? 0 : (y0 > 255 ? 255 : y0);
  int x1 = x0 + 1 > 255 ? 255 : x0 + 1;
  int y1 = y0 + 1 > 255 ? 255 : y0 + 1;
  float w00 = (1.f - wx) * (1.f - wy);
  float w01 = wx * (1.f - wy);
  float w10 = (1.f - wx) * wy;
  float w11 = wx * wy;

  const __half* __restrict__ P = T + (size_t)p * PLANE_ELEMS;
  int r00 = (y0 * 256 + x0) * 256, r01 = (y0 * 256 + x1) * 256;
  int r10 = (y1 * 256 + x0) * 256, r11 = (y1 * 256 + x1) * 256;
  int ore = t * 16;
  int oim = 128 + t * 16;

  f4 a0 = *(const f4*)(P + r00 + ore),     a1 = *(const f4*)(P + r00 + ore + 8);
  f4 a2 = *(const f4*)(P + r00 + oim),     a3 = *(const f4*)(P + r00 + oim + 8);
  f4 b0 = *(const f4*)(P + r01 + ore),     b1 = *(const f4*)(P + r01 + ore + 8);
  f4 b2 = *(const f4*)(P + r01 + oim),     b3 = *(const f4*)(P + r01 + oim + 8);
  f4 c0v = *(const f4*)(P + r10 + ore),    c1v = *(const f4*)(P + r10 + ore + 8);
  f4 c2v = *(const f4*)(P + r10 + oim),    c3v = *(const f4*)(P + r10 + oim + 8);
  f4 d0 = *(const f4*)(P + r11 + ore),     d1 = *(const f4*)(P + r11 + ore + 8);
  f4 d2 = *(const f4*)(P + r11 + oim),     d3 = *(const f4*)(P + r11 + oim + 8);

  __half2 hw00 = __float2half2_rn(w00), hw01 = __float2half2_rn(w01);
  __half2 hw10 = __float2half2_rn(w10), hw11 = __float2half2_rn(w11);

  __half2 bre[8], bim[8];
#pragma unroll
  for (int q = 0; q < 4; ++q) {
    __half2 v;
    v = __hmul2(((const __half2*)&a0)[q], hw00);
    v = __hfma2(((const __half2*)&b0)[q],  hw01, v);
    v = __hfma2(((const __half2*)&c0v)[q], hw10, v);
    bre[q] = __hfma2(((const __half2*)&d0)[q], hw11, v);

    v = __hmul2(((const __half2*)&a1)[q], hw00);
    v = __hfma2(((const __half2*)&b1)[q],  hw01, v);
    v = __hfma2(((const __half2*)&c1v)[q], hw10, v);
    bre[q + 4] = __hfma2(((const __half2*)&d1)[q], hw11, v);

    v = __hmul2(((const __half2*)&a2)[q], hw00);
    v = __hfma2(((const __half2*)&b2)[q],  hw01, v);
    v = __hfma2(((const __half2*)&c2v)[q], hw10, v);
    bim[q] = __hfma2(((const __half2*)&d2)[q], hw11, v);

    v = __hmul2(((const __half2*)&a3)[q], hw00);
    v = __hfma2(((const __half2*)&b3)[q],  hw01, v);
    v = __hfma2(((const __half2*)&c3v)[q], hw10, v);
    bim[q + 4] = __hfma2(((const __half2*)&d3)[q], hw11, v);
  }

  float fre[16], fim[16];
#pragma unroll
  for (int q = 0; q < 8; ++q) {
    float2 vr = __half22float2(bre[q]);
    float2 vi = __half22float2(bim[q]);
    fre[2 * q] = vr.x; fre[2 * q + 1] = vr.y;
    fim[2 * q] = vi.x; fim[2 * q + 1] = vi.y;
  }

  float cs = (ax + 1.f) * 0.5f * 255.f;
  float th = 6.283185307179586f * cs * (1.f / 256.f);
  float s, c;
  __sincosf(th, &s, &c);
  float aR0 = fre[0], aR1 = fre[8];
  float aI0 = 0.f,    aI1 = 0.f;
#pragma unroll
  for (int r = 1; r < 8; ++r) {
    aR0 += fre[r] * c;     aR1 += fre[8 + r] * c;
    aI0 += fim[r] * s;     aI1 += fim[8 + r] * s;
    if (r < 7) {
      float c2 = c + c;
      float cn = c2 * c - 1.f;
      s = c2 * s;
      c = cn;
    }
  }

  *(__half2*)(partial + ((size_t)p * NPTS + n) * 16 + 2 * t) =
      __floats2half2_rn(aR0 - aI0, aR1 - aI1);
}

__device__ __forceinline__ void scat_point(
    int p, int n, const float* __restrict__ inputs,
    unsigned* __restrict__ hist, unsigned* __restrict__ idx) {
  float c0 = inputs[n * 3 + 0], c1 = inputs[n * 3 + 1], c2 = inputs[n * 3 + 2];
  float gx, gy, ax;
  plane_xy(p, c0, c1, c2, gx, gy, ax);
  int key = (cell_of(gy) << 8) | cell_of(gx);
  unsigned pos = atomicAdd(&hist[p * 65536 + key], 1u);
  idx[(size_t)p * NPTS + pos] = (unsigned)n;
}

// ---------------------------------------------------------------------------
// K1 fat kernel: trans (blocks 0-1535) ∥ hist (blocks 1536-2303). [R12]
// ---------------------------------------------------------------------------
__global__ __launch_bounds__(256) void PREFFFT_fat1_k(
    const float* __restrict__ Pu, const float* __restrict__ Pv,
    const float* __restrict__ Pw, __half* __restrict__ dst0,
    const float* __restrict__ inputs, unsigned* __restrict__ hist) {
  __shared__ unsigned tile[128 * 36];
  const int bx = blockIdx.x;
  const int tid = threadIdx.x;
  if (bx < 1536) {
    int bz = bx / 512;
    int rem = bx - bz * 512;
    int by = rem >> 7;
    int bxx = rem & 127;
    const float* src = bz == 0 ? Pu : (bz == 1 ? Pv : Pw);
    __half* dst = dst0 + (size_t)bz * PLANE_ELEMS;
    const unsigned hwbase = bxx * 512u;
    const unsigned c0 = by * 64u;
    f4 vaA[4], vbA[4], vaB[4], vbB[4];
    trans_load(src, c0, hwbase, tid, vaA, vbA);
    trans_load(src, c0, hwbase + 128u, tid, vaB, vbB);
    trans_proc(tile, dst, c0, hwbase, tid, vaA, vbA);
    trans_load(src, c0, hwbase + 256u, tid, vaA, vbA);
    trans_proc(tile, dst, c0, hwbase + 128u, tid, vaB, vbB);
    trans_load(src, c0, hwbase + 384u, tid, vaB, vbB);
    trans_proc(tile, dst, c0, hwbase + 256u, tid, vaA, vbA);
    trans_proc(tile, dst, c0, hwbase + 384u, tid, vaB, vbB);
  } else {
    int hb = bx - 1536;
#pragma unroll
    for (int it = 0; it < 4; ++it) {
      int item = hb * 1024 + it * 256 + tid;
      int n = item & (NPTS - 1);
      int p = item >> 18;
      float c0 = inputs[n * 3 + 0], c1 = inputs[n * 3 + 1], c2 = inputs[n * 3 + 2];
      float gx, gy, ax;
      plane_xy(p, c0, c1, c2, gx, gy, ax);
      int key = (cell_of(gy) << 8) | cell_of(gx);
      atomicAdd(&hist[p * 65536 + key], 1u);
    }
  }
}

// ---------------------------------------------------------------------------
// Scan: exclusive prefix over 65536 bins; one block per plane.
// ---------------------------------------------------------------------------
__global__ __launch_bounds__(1024) void PREFFFT_scan_k(unsigned* __restrict__ hist) {
  __shared__ unsigned part[1024];
  unsigned* h = hist + (size_t)blockIdx.x * 65536;
  int t = threadIdx.x;
  unsigned s = 0;
#pragma unroll 8
  for (int i = 0; i < 64; ++i) s += h[t * 64 + i];
  part[t] = s;
  __syncthreads();
  for (int off = 1; off < 1024; off <<= 1) {
    unsigned v = (t >= off) ? part[t - off] : 0u;
    __syncthreads();
    part[t] += v;
    __syncthreads();
  }
  unsigned run = (t == 0) ? 0u : part[t - 1];
#pragma unroll 8
  for (int i = 0; i < 64; ++i) {
    unsigned c = h[t * 64 + i];
    h[t * 64 + i] = run;
    run += c;
  }
}

// ---------------------------------------------------------------------------
// Standalone scatter for plane 0 (the only latency-exposed one).
// ---------------------------------------------------------------------------
__global__ __launch_bounds__(256) void PREFFFT_scat1_k(
    const float* __restrict__ inputs, unsigned* __restrict__ hist,
    unsigned* __restrict__ idx) {
  int n = blockIdx.x * 256 + threadIdx.x;
  scat_point(0, n, inputs, hist, idx);
}

// ---------------------------------------------------------------------------
// Fat pipeline kernel: blocks [0,1024) = scat(plane sp+1) — dispatched first,
// latency hides under the 8192 samp(plane sp) blocks [1024, 9216).
// ---------------------------------------------------------------------------
__global__ __launch_bounds__(256) void PREFFFT_fat2_k(
    unsigned* __restrict__ idx, const float* __restrict__ inputs,
    const __half* __restrict__ T, __half* __restrict__ partial,
    unsigned* __restrict__ hist, int sp) {
  int bx = blockIdx.x;
  if (bx < 1024) {
    int n = bx * 256 + threadIdx.x;
    scat_point(sp + 1, n, inputs, hist, idx);
  } else {
    int b = bx - 1024;                        // 0..8191
    int lbx = (b & 7) * 1024 + (b >> 3);      // XCD-contiguous chunks
    int slot = lbx * 32 + ((int)threadIdx.x >> 3);
    samp_point(sp, slot, threadIdx.x & 7, idx, inputs, T, partial);
  }
}

// ---------------------------------------------------------------------------
// Final sample pass (plane 2 alone). grid 8192.
// ---------------------------------------------------------------------------
__global__ __launch_bounds__(256) void PREFFFT_samp1_k(
    const unsigned* __restrict__ idx, const float* __restrict__ inputs,
    const __half* __restrict__ T, __half* __restrict__ partial) {
  int b = blockIdx.x;
  int lbx = (b & 7) * 1024 + (b >> 3);
  int slot = lbx * 32 + ((int)threadIdx.x >> 3);
  samp_point(2, slot, threadIdx.x & 7, idx, inputs, T, partial);
}

// ---------------------------------------------------------------------------
// Reduce: out = sum of 3 fp16 partials, f32 output. 8 outputs/thread.
// ---------------------------------------------------------------------------
__global__ __launch_bounds__(256) void PREFFFT_red_k(
    const __half* __restrict__ part, float* __restrict__ out) {
  size_t i = (size_t)blockIdx.x * 256 + threadIdx.x;
  const size_t PS = (size_t)NPTS * 16;
  union H8 { u4 v; __half2 h[4]; };
  H8 a, b, c;
  a.v = *(const u4*)(part + i * 8);
  b.v = *(const u4*)(part + PS + i * 8);
  c.v = *(const u4*)(part + 2 * PS + i * 8);
  f4 o0, o1;
#pragma unroll
  for (int k = 0; k < 4; ++k) {
    float2 fa = __half22float2(a.h[k]);
    float2 fb = __half22float2(b.h[k]);
    float2 fc = __half22float2(c.h[k]);
    float lo = fa.x + fb.x + fc.x;
    float hi = fa.y + fb.y + fc.y;
    if (k < 2) { o0[2 * k] = lo; o0[2 * k + 1] = hi; }
    else       { o1[2 * (k - 2)] = lo; o1[2 * (k - 2) + 1] = hi; }
  }
  ((f4*)out)[i * 2] = o0;
  ((f4*)out)[i * 2 + 1] = o1;
}

// ---------------------------------------------------------------------------
// Fallback (ws too small): original (C,H,W) fp32 direct, slow but correct.
// ---------------------------------------------------------------------------
__global__ __launch_bounds__(256) void PREFFFT_fallback_k(
    const float* __restrict__ inputs, const float* __restrict__ Tu,
    const float* __restrict__ Tv, const float* __restrict__ Tw,
    float* __restrict__ out) {
  int gtid = blockIdx.x * 256 + threadIdx.x;
  int n = gtid >> 5;
  int t = threadIdx.x & 31;
  const bool is_re = t < 16;
  float c0 = inputs[n * 3 + 0], c1 = inputs[n * 3 + 1], c2 = inputs[n * 3 + 2];
  const float* PL[3] = {Tu, Tv, Tw};
  float acc = 0.f;
#pragma unroll
  for (int p = 0; p < 3; ++p) {
    float gx, gy, ax;
    plane_xy(p, c0, c1, c2, gx, gy, ax);
    float ix = (gx + 1.f) * 0.5f * 255.f;
    float iy = (gy + 1.f) * 0.5f * 255.f;
    float x0f = floorf(ix), y0f = floorf(iy);
    float wx = ix - x0f, wy = iy - y0f;
    int x0 = (int)x0f; x0 = x0 < 0 ? 0 : (x0 > 255 ? 255 : x0);
    int y0 = (int)y0f; y0 = y0 < 0 ? 0 : (y0 > 255 ? 255 : y0);
    int x1 = x0 + 1 > 255 ? 255 : x0 + 1;
    int y1 = y0 + 1 > 255 ? 255 : y0 + 1;
    float w00 = (1.f - wx) * (1.f - wy), w01 = wx * (1.f - wy);
    float w10 = (1.f - wx) * wy, w11 = wx * wy;
    int i00 = y0 * 256 + x0, i01 = y0 * 256 + x1;
    int i10 = y1 * 256 + x0, i11 = y1 * 256 + x1;
    float b[8];
#pragma unroll
    for (int j = 0; j < 8; ++j) {
      const float* base = PL[p] + (size_t)(t * 8 + j) * 65536u;
      b[j] = w00 * base[i00] + w01 * base[i01] + w10 * base[i10] + w11 * base[i11];
    }
    float csv = (ax + 1.f) * 0.5f * 255.f;
    float theta1 = 6.283185307179586f * csv * (1.f / 256.f);
    float partial = is_re ? b[0] : 0.f;
#pragma unroll
    for (int r = 1; r < 8; ++r) {
      float thr = theta1 * (float)(1 << (r - 1));
      float s, c;
      __sincosf(thr, &s, &c);
      partial += b[r] * (is_re ? c : s);
    }
    float other = __shfl_xor(partial, 16);
    acc += partial - other;
  }
  if (is_re) out[n * 16 + t] = acc;
}

extern "C" void kernel_launch(void* const* d_in, const int* in_sizes, int n_in,
                              void* d_out, int out_size, void* d_ws, size_t ws_size,
                              hipStream_t stream) {
  const float* inputs = (const float*)d_in[0];
  const float* Pu = (const float*)d_in[1];
  const float* Pv = (const float*)d_in[2];
  const float* Pw = (const float*)d_in[3];
  float* out = (float*)d_out;

  if (ws_size >= WS_NEED) {
    char* ws = (char*)d_ws;
    __half*   T       = (__half*)ws;
    unsigned* idx     = (unsigned*)(ws + OFF_IDX);
    __half*   partial = (__half*)(ws + OFF_PARTIAL);
    unsigned* hist    = (unsigned*)(ws + OFF_HIST);

    hipMemsetAsync(hist, 0, (size_t)3 * 65536 * 4, stream);
    PREFFFT_fat1_k<<<2304, 256, 0, stream>>>(Pu, Pv, Pw, T, inputs, hist);
    PREFFFT_scan_k<<<3, 1024, 0, stream>>>(hist);
    PREFFFT_scat1_k<<<1024, 256, 0, stream>>>(inputs, hist, idx);
    PREFFFT_fat2_k<<<9216, 256, 0, stream>>>(idx, inputs, T, partial, hist, 0);
    PREFFFT_fat2_k<<<9216, 256, 0, stream>>>(idx, inputs, T, partial, hist, 1);
    PREFFFT_samp1_k<<<8192, 256, 0, stream>>>(idx, inputs, T, partial);
    PREFFFT_red_k<<<2048, 256, 0, stream>>>(partial, out);
  } else {
    PREFFFT_fallback_k<<<NPTS / 8, 256, 0, stream>>>(inputs, Pu, Pv, Pw, out);
  }
}

// Round 14
// 200.356 us; speedup vs baseline: 1.1554x; 1.0390x over previous
//
#include <hip/hip_runtime.h>
#include <hip/hip_fp16.h>
#include <math.h>

#define NPTS 262144
#define PLANE_ELEMS 16777216u   // 256*256*256

typedef __attribute__((ext_vector_type(4))) float f4;
typedef __attribute__((ext_vector_type(4))) unsigned int u4;

// ws layout (bytes):
//   [0, 96 MB)        : fp16 transposed planes (3 x 32 MB), layout [hw][c=256]
//   +3.1 MB           : idx u32[3][NPTS]  (sorted pos -> original n)
//   +25.17 MB         : partial fp16[3][NPTS][16]
//   +0.75 MB          : hist unsigned[3][65536]
#define OFF_IDX      (3ull * PLANE_ELEMS * 2ull)
#define OFF_PARTIAL  (OFF_IDX + (size_t)3 * NPTS * 4)
#define OFF_HIST     (OFF_PARTIAL + (size_t)3 * NPTS * 16 * 2)
#define WS_NEED      (OFF_HIST + (size_t)3 * 65536 * 4)

__device__ __forceinline__ void plane_xy(int p, float c0, float c1, float c2,
                                         float& gx, float& gy, float& ax) {
  if (p == 0)      { gx = c1; gy = c2; ax = c0; }
  else if (p == 1) { gx = c0; gy = c2; ax = c1; }
  else             { gx = c0; gy = c1; ax = c2; }
}

__device__ __forceinline__ int cell_of(float g) {
  float i = (g + 1.f) * 0.5f * 255.f;
  int x0 = (int)floorf(i);
  return x0 < 0 ? 0 : (x0 > 255 ? 255 : x0);
}

// ---------------------------------------------------------------------------
// Trans helpers (R10-verified).
// ---------------------------------------------------------------------------
__device__ __forceinline__ void trans_load(const float* __restrict__ src,
                                           unsigned c0, unsigned hw0, int tid,
                                           f4 (&va)[4], f4 (&vb)[4]) {
#pragma unroll
  for (int j = 0; j < 4; ++j) {
    int idx = j * 256 + tid;
    int rp = idx >> 5;
    int q = idx & 31;
    const f4* base = (const f4*)(src + (size_t)(c0 + 2 * rp) * 65536u + hw0 + 4 * q);
    va[j] = __builtin_nontemporal_load(base);
    vb[j] = __builtin_nontemporal_load(base + 16384);
  }
}

__device__ __forceinline__ void trans_proc(unsigned* tile, __half* dst,
                                           unsigned c0, unsigned hw0, int tid,
                                           f4 (&va)[4], f4 (&vb)[4]) {
#pragma unroll
  for (int j = 0; j < 4; ++j) {
    int idx = j * 256 + tid;
    int rp = idx >> 5;
    int q = idx & 31;
#pragma unroll
    for (int k = 0; k < 4; ++k) {
      int hw = 4 * q + k;
      __half2 h = __floats2half2_rn(va[j][k], vb[j][k]);
      tile[hw * 36 + (rp ^ (hw >> 3))] = *(unsigned*)&h;
    }
  }
  __syncthreads();
  int seg = tid & 7;
#pragma unroll
  for (int jj = 0; jj < 4; ++jj) {
    int hw = jj * 32 + (tid >> 3);
    int s = hw >> 3;
    u4 v = *(const u4*)(tile + hw * 36 + 4 * ((seg ^ (s >> 2)) & 7));
    u4 o;
    switch (s & 3) {
      case 0: o = v; break;
      case 1: o = u4{v.y, v.x, v.w, v.z}; break;
      case 2: o = u4{v.z, v.w, v.x, v.y}; break;
      default: o = u4{v.w, v.z, v.y, v.x}; break;
    }
    *(u4*)((char*)dst + ((size_t)(hw0 + hw) * 256u + c0) * 2u + seg * 16u) = o;
  }
  __syncthreads();
}

// ---------------------------------------------------------------------------
// Sample body (R12-verified): one (plane, sorted slot) by an 8-lane group.
// ---------------------------------------------------------------------------
__device__ __forceinline__ void samp_point(
    int p, int slot, int t, const unsigned* __restrict__ idx,
    const float* __restrict__ inputs, const __half* __restrict__ T,
    __half* __restrict__ partial) {
  unsigned n = idx[(size_t)p * NPTS + slot];
  float c0 = inputs[n * 3 + 0], c1 = inputs[n * 3 + 1], c2 = inputs[n * 3 + 2];
  float gx, gy, ax;
  plane_xy(p, c0, c1, c2, gx, gy, ax);

  float ix = (gx + 1.f) * 0.5f * 255.f;
  float iy = (gy + 1.f) * 0.5f * 255.f;
  float x0f = floorf(ix), y0f = floorf(iy);
  float wx = ix - x0f, wy = iy - y0f;
  int x0 = (int)x0f; x0 = x0 < 0 ? 0 : (x0 > 255 ? 255 : x0);
  int y0 = (int)y0f; y0 = y0 < 0 ? 0 : (y0 > 255 ? 255 : y0);
  int x1 = x0 + 1 > 255 ? 255 : x0 + 1;
  int y1 = y0 + 1 > 255 ? 255 : y0 + 1;
  float w00 = (1.f - wx) * (1.f - wy);
  float w01 = wx * (1.f - wy);
  float w10 = (1.f - wx) * wy;
  float w11 = wx * wy;

  const __half* __restrict__ P = T + (size_t)p * PLANE_ELEMS;
  int r00 = (y0 * 256 + x0) * 256, r01 = (y0 * 256 + x1) * 256;
  int r10 = (y1 * 256 + x0) * 256, r11 = (y1 * 256 + x1) * 256;
  int ore = t * 16;
  int oim = 128 + t * 16;

  f4 a0 = *(const f4*)(P + r00 + ore),     a1 = *(const f4*)(P + r00 + ore + 8);
  f4 a2 = *(const f4*)(P + r00 + oim),     a3 = *(const f4*)(P + r00 + oim + 8);
  f4 b0 = *(const f4*)(P + r01 + ore),     b1 = *(const f4*)(P + r01 + ore + 8);
  f4 b2 = *(const f4*)(P + r01 + oim),     b3 = *(const f4*)(P + r01 + oim + 8);
  f4 c0v = *(const f4*)(P + r10 + ore),    c1v = *(const f4*)(P + r10 + ore + 8);
  f4 c2v = *(const f4*)(P + r10 + oim),    c3v = *(const f4*)(P + r10 + oim + 8);
  f4 d0 = *(const f4*)(P + r11 + ore),     d1 = *(const f4*)(P + r11 + ore + 8);
  f4 d2 = *(const f4*)(P + r11 + oim),     d3 = *(const f4*)(P + r11 + oim + 8);

  __half2 hw00 = __float2half2_rn(w00), hw01 = __float2half2_rn(w01);
  __half2 hw10 = __float2half2_rn(w10), hw11 = __float2half2_rn(w11);

  __half2 bre[8], bim[8];
#pragma unroll
  for (int q = 0; q < 4; ++q) {
    __half2 v;
    v = __hmul2(((const __half2*)&a0)[q], hw00);
    v = __hfma2(((const __half2*)&b0)[q],  hw01, v);
    v = __hfma2(((const __half2*)&c0v)[q], hw10, v);
    bre[q] = __hfma2(((const __half2*)&d0)[q], hw11, v);

    v = __hmul2(((const __half2*)&a1)[q], hw00);
    v = __hfma2(((const __half2*)&b1)[q],  hw01, v);
    v = __hfma2(((const __half2*)&c1v)[q], hw10, v);
    bre[q + 4] = __hfma2(((const __half2*)&d1)[q], hw11, v);

    v = __hmul2(((const __half2*)&a2)[q], hw00);
    v = __hfma2(((const __half2*)&b2)[q],  hw01, v);
    v = __hfma2(((const __half2*)&c2v)[q], hw10, v);
    bim[q] = __hfma2(((const __half2*)&d2)[q], hw11, v);

    v = __hmul2(((const __half2*)&a3)[q], hw00);
    v = __hfma2(((const __half2*)&b3)[q],  hw01, v);
    v = __hfma2(((const __half2*)&c3v)[q], hw10, v);
    bim[q + 4] = __hfma2(((const __half2*)&d3)[q], hw11, v);
  }

  float fre[16], fim[16];
#pragma unroll
  for (int q = 0; q < 8; ++q) {
    float2 vr = __half22float2(bre[q]);
    float2 vi = __half22float2(bim[q]);
    fre[2 * q] = vr.x; fre[2 * q + 1] = vr.y;
    fim[2 * q] = vi.x; fim[2 * q + 1] = vi.y;
  }

  float cs = (ax + 1.f) * 0.5f * 255.f;
  float th = 6.283185307179586f * cs * (1.f / 256.f);
  float s, c;
  __sincosf(th, &s, &c);
  float aR0 = fre[0], aR1 = fre[8];
  float aI0 = 0.f,    aI1 = 0.f;
#pragma unroll
  for (int r = 1; r < 8; ++r) {
    aR0 += fre[r] * c;     aR1 += fre[8 + r] * c;
    aI0 += fim[r] * s;     aI1 += fim[8 + r] * s;
    if (r < 7) {
      float c2 = c + c;
      float cn = c2 * c - 1.f;
      s = c2 * s;
      c = cn;
    }
  }

  *(__half2*)(partial + ((size_t)p * NPTS + n) * 16 + 2 * t) =
      __floats2half2_rn(aR0 - aI0, aR1 - aI1);
}

__device__ __forceinline__ void scat_point(
    int p, int n, const float* __restrict__ inputs,
    unsigned* __restrict__ hist, unsigned* __restrict__ idx) {
  float c0 = inputs[n * 3 + 0], c1 = inputs[n * 3 + 1], c2 = inputs[n * 3 + 2];
  float gx, gy, ax;
  plane_xy(p, c0, c1, c2, gx, gy, ax);
  int key = (cell_of(gy) << 8) | cell_of(gx);
  unsigned pos = atomicAdd(&hist[p * 65536 + key], 1u);
  idx[(size_t)p * NPTS + pos] = (unsigned)n;
}

// ---------------------------------------------------------------------------
// K1 fat kernel: trans ∥ hist. R14: hist blocks INTERLEAVED (bx%3==2) so
// they are co-resident with trans blocks from t=0 — R13 put them at the end
// of the grid, where dispatch order made hist a serial tail (~11 us).
// grid 2304, block 256.
// ---------------------------------------------------------------------------
__global__ __launch_bounds__(256) void PREFFFT_fat1_k(
    const float* __restrict__ Pu, const float* __restrict__ Pv,
    const float* __restrict__ Pw, __half* __restrict__ dst0,
    const float* __restrict__ inputs, unsigned* __restrict__ hist) {
  __shared__ unsigned tile[128 * 36];
  const int bx = blockIdx.x;
  const int tid = threadIdx.x;
  if ((bx % 3) != 2) {
    int ti = (bx / 3) * 2 + (bx % 3);   // 0..1535
    int bz = ti / 512;
    int rem = ti - bz * 512;
    int by = rem >> 7;
    int bxx = rem & 127;
    const float* src = bz == 0 ? Pu : (bz == 1 ? Pv : Pw);
    __half* dst = dst0 + (size_t)bz * PLANE_ELEMS;
    const unsigned hwbase = bxx * 512u;
    const unsigned c0 = by * 64u;
    f4 vaA[4], vbA[4], vaB[4], vbB[4];
    trans_load(src, c0, hwbase, tid, vaA, vbA);
    trans_load(src, c0, hwbase + 128u, tid, vaB, vbB);
    trans_proc(tile, dst, c0, hwbase, tid, vaA, vbA);
    trans_load(src, c0, hwbase + 256u, tid, vaA, vbA);
    trans_proc(tile, dst, c0, hwbase + 128u, tid, vaB, vbB);
    trans_load(src, c0, hwbase + 384u, tid, vaB, vbB);
    trans_proc(tile, dst, c0, hwbase + 256u, tid, vaA, vbA);
    trans_proc(tile, dst, c0, hwbase + 384u, tid, vaB, vbB);
  } else {
    int hb = bx / 3;                    // 0..767
#pragma unroll
    for (int it = 0; it < 4; ++it) {
      int item = hb * 1024 + it * 256 + tid;
      int n = item & (NPTS - 1);
      int p = item >> 18;
      float c0 = inputs[n * 3 + 0], c1 = inputs[n * 3 + 1], c2 = inputs[n * 3 + 2];
      float gx, gy, ax;
      plane_xy(p, c0, c1, c2, gx, gy, ax);
      int key = (cell_of(gy) << 8) | cell_of(gx);
      atomicAdd(&hist[p * 65536 + key], 1u);
    }
  }
}

// ---------------------------------------------------------------------------
// Scan: exclusive prefix over 65536 bins; one block per plane.
// ---------------------------------------------------------------------------
__global__ __launch_bounds__(1024) void PREFFFT_scan_k(unsigned* __restrict__ hist) {
  __shared__ unsigned part[1024];
  unsigned* h = hist + (size_t)blockIdx.x * 65536;
  int t = threadIdx.x;
  unsigned s = 0;
#pragma unroll 8
  for (int i = 0; i < 64; ++i) s += h[t * 64 + i];
  part[t] = s;
  __syncthreads();
  for (int off = 1; off < 1024; off <<= 1) {
    unsigned v = (t >= off) ? part[t - off] : 0u;
    __syncthreads();
    part[t] += v;
    __syncthreads();
  }
  unsigned run = (t == 0) ? 0u : part[t - 1];
#pragma unroll 8
  for (int i = 0; i < 64; ++i) {
    unsigned c = h[t * 64 + i];
    h[t * 64 + i] = run;
    run += c;
  }
}

// ---------------------------------------------------------------------------
// Standalone scatter for plane 0 (the only latency-exposed one).
// ---------------------------------------------------------------------------
__global__ __launch_bounds__(256) void PREFFFT_scat1_k(
    const float* __restrict__ inputs, unsigned* __restrict__ hist,
    unsigned* __restrict__ idx) {
  int n = blockIdx.x * 256 + threadIdx.x;
  scat_point(0, n, inputs, hist, idx);
}

// ---------------------------------------------------------------------------
// Fat pipeline kernel: blocks [0,1024) = scat(plane sp+1) — dispatched first,
// latency hides under the 8192 samp(plane sp) blocks [1024, 9216).
// ---------------------------------------------------------------------------
__global__ __launch_bounds__(256) void PREFFFT_fat2_k(
    unsigned* __restrict__ idx, const float* __restrict__ inputs,
    const __half* __restrict__ T, __half* __restrict__ partial,
    unsigned* __restrict__ hist, int sp) {
  int bx = blockIdx.x;
  if (bx < 1024) {
    int n = bx * 256 + threadIdx.x;
    scat_point(sp + 1, n, inputs, hist, idx);
  } else {
    int b = bx - 1024;                        // 0..8191
    int lbx = (b & 7) * 1024 + (b >> 3);      // XCD-contiguous chunks
    int slot = lbx * 32 + ((int)threadIdx.x >> 3);
    samp_point(sp, slot, threadIdx.x & 7, idx, inputs, T, partial);
  }
}

// ---------------------------------------------------------------------------
// Final sample pass (plane 2 alone). grid 8192.
// ---------------------------------------------------------------------------
__global__ __launch_bounds__(256) void PREFFFT_samp1_k(
    const unsigned* __restrict__ idx, const float* __restrict__ inputs,
    const __half* __restrict__ T, __half* __restrict__ partial) {
  int b = blockIdx.x;
  int lbx = (b & 7) * 1024 + (b >> 3);
  int slot = lbx * 32 + ((int)threadIdx.x >> 3);
  samp_point(2, slot, threadIdx.x & 7, idx, inputs, T, partial);
}

// ---------------------------------------------------------------------------
// Reduce: out = sum of 3 fp16 partials, f32 output. 8 outputs/thread.
// ---------------------------------------------------------------------------
__global__ __launch_bounds__(256) void PREFFFT_red_k(
    const __half* __restrict__ part, float* __restrict__ out) {
  size_t i = (size_t)blockIdx.x * 256 + threadIdx.x;
  const size_t PS = (size_t)NPTS * 16;
  union H8 { u4 v; __half2 h[4]; };
  H8 a, b, c;
  a.v = *(const u4*)(part + i * 8);
  b.v = *(const u4*)(part + PS + i * 8);
  c.v = *(const u4*)(part + 2 * PS + i * 8);
  f4 o0, o1;
#pragma unroll
  for (int k = 0; k < 4; ++k) {
    float2 fa = __half22float2(a.h[k]);
    float2 fb = __half22float2(b.h[k]);
    float2 fc = __half22float2(c.h[k]);
    float lo = fa.x + fb.x + fc.x;
    float hi = fa.y + fb.y + fc.y;
    if (k < 2) { o0[2 * k] = lo; o0[2 * k + 1] = hi; }
    else       { o1[2 * (k - 2)] = lo; o1[2 * (k - 2) + 1] = hi; }
  }
  ((f4*)out)[i * 2] = o0;
  ((f4*)out)[i * 2 + 1] = o1;
}

// ---------------------------------------------------------------------------
// Fallback (ws too small): original (C,H,W) fp32 direct, slow but correct.
// ---------------------------------------------------------------------------
__global__ __launch_bounds__(256) void PREFFFT_fallback_k(
    const float* __restrict__ inputs, const float* __restrict__ Tu,
    const float* __restrict__ Tv, const float* __restrict__ Tw,
    float* __restrict__ out) {
  int gtid = blockIdx.x * 256 + threadIdx.x;
  int n = gtid >> 5;
  int t = threadIdx.x & 31;
  const bool is_re = t < 16;
  float c0 = inputs[n * 3 + 0], c1 = inputs[n * 3 + 1], c2 = inputs[n * 3 + 2];
  const float* PL[3] = {Tu, Tv, Tw};
  float acc = 0.f;
#pragma unroll
  for (int p = 0; p < 3; ++p) {
    float gx, gy, ax;
    plane_xy(p, c0, c1, c2, gx, gy, ax);
    float ix = (gx + 1.f) * 0.5f * 255.f;
    float iy = (gy + 1.f) * 0.5f * 255.f;
    float x0f = floorf(ix), y0f = floorf(iy);
    float wx = ix - x0f, wy = iy - y0f;
    int x0 = (int)x0f; x0 = x0 < 0 ? 0 : (x0 > 255 ? 255 : x0);
    int y0 = (int)y0f; y0 = y0 < 0 ? 0 : (y0 > 255 ? 255 : y0);
    int x1 = x0 + 1 > 255 ? 255 : x0 + 1;
    int y1 = y0 + 1 > 255 ? 255 : y0 + 1;
    float w00 = (1.f - wx) * (1.f - wy), w01 = wx * (1.f - wy);
    float w10 = (1.f - wx) * wy, w11 = wx * wy;
    int i00 = y0 * 256 + x0, i01 = y0 * 256 + x1;
    int i10 = y1 * 256 + x0, i11 = y1 * 256 + x1;
    float b[8];
#pragma unroll
    for (int j = 0; j < 8; ++j) {
      const float* base = PL[p] + (size_t)(t * 8 + j) * 65536u;
      b[j] = w00 * base[i00] + w01 * base[i01] + w10 * base[i10] + w11 * base[i11];
    }
    float csv = (ax + 1.f) * 0.5f * 255.f;
    float theta1 = 6.283185307179586f * csv * (1.f / 256.f);
    float partial = is_re ? b[0] : 0.f;
#pragma unroll
    for (int r = 1; r < 8; ++r) {
      float thr = theta1 * (float)(1 << (r - 1));
      float s, c;
      __sincosf(thr, &s, &c);
      partial += b[r] * (is_re ? c : s);
    }
    float other = __shfl_xor(partial, 16);
    acc += partial - other;
  }
  if (is_re) out[n * 16 + t] = acc;
}

extern "C" void kernel_launch(void* const* d_in, const int* in_sizes, int n_in,
                              void* d_out, int out_size, void* d_ws, size_t ws_size,
                              hipStream_t stream) {
  const float* inputs = (const float*)d_in[0];
  const float* Pu = (const float*)d_in[1];
  const float* Pv = (const float*)d_in[2];
  const float* Pw = (const float*)d_in[3];
  float* out = (float*)d_out;

  if (ws_size >= WS_NEED) {
    char* ws = (char*)d_ws;
    __half*   T       = (__half*)ws;
    unsigned* idx     = (unsigned*)(ws + OFF_IDX);
    __half*   partial = (__half*)(ws + OFF_PARTIAL);
    unsigned* hist    = (unsigned*)(ws + OFF_HIST);

    hipMemsetAsync(hist, 0, (size_t)3 * 65536 * 4, stream);
    PREFFFT_fat1_k<<<2304, 256, 0, stream>>>(Pu, Pv, Pw, T, inputs, hist);
    PREFFFT_scan_k<<<3, 1024, 0, stream>>>(hist);
    PREFFFT_scat1_k<<<1024, 256, 0, stream>>>(inputs, hist, idx);
    PREFFFT_fat2_k<<<9216, 256, 0, stream>>>(idx, inputs, T, partial, hist, 0);
    PREFFFT_fat2_k<<<9216, 256, 0, stream>>>(idx, inputs, T, partial, hist, 1);
    PREFFFT_samp1_k<<<8192, 256, 0, stream>>>(idx, inputs, T, partial);
    PREFFFT_red_k<<<2048, 256, 0, stream>>>(partial, out);
  } else {
    PREFFFT_fallback_k<<<NPTS / 8, 256, 0, stream>>>(inputs, Pu, Pv, Pw, out);
  }
}

// Round 15
// 194.963 us; speedup vs baseline: 1.1874x; 1.0277x over previous
//
#include <hip/hip_runtime.h>
#include <hip/hip_fp16.h>
#include <math.h>

#define NPTS 262144
#define PLANE_ELEMS 16777216u   // 256*256*256

typedef __attribute__((ext_vector_type(4))) float f4;
typedef __attribute__((ext_vector_type(4))) unsigned int u4;

// ws layout (bytes):
//   [0, 96 MB)        : fp16 transposed planes (3 x 32 MB), layout [hw][c=256]
//   +3.1 MB           : idx u32[3][NPTS]  (sorted pos -> original n)
//   +16.8 MB          : partial fp16[2][NPTS][16]  (planes 0,1 only)
//   +0.75 MB          : hist unsigned[3][65536]
#define OFF_IDX      (3ull * PLANE_ELEMS * 2ull)
#define OFF_PARTIAL  (OFF_IDX + (size_t)3 * NPTS * 4)
#define OFF_HIST     (OFF_PARTIAL + (size_t)2 * NPTS * 16 * 2)
#define WS_NEED      (OFF_HIST + (size_t)3 * 65536 * 4)

__device__ __forceinline__ void plane_xy(int p, float c0, float c1, float c2,
                                         float& gx, float& gy, float& ax) {
  if (p == 0)      { gx = c1; gy = c2; ax = c0; }
  else if (p == 1) { gx = c0; gy = c2; ax = c1; }
  else             { gx = c0; gy = c1; ax = c2; }
}

__device__ __forceinline__ int cell_of(float g) {
  float i = (g + 1.f) * 0.5f * 255.f;
  int x0 = (int)floorf(i);
  return x0 < 0 ? 0 : (x0 > 255 ? 255 : x0);
}

// ---------------------------------------------------------------------------
// Trans helpers (R10-verified).
// ---------------------------------------------------------------------------
__device__ __forceinline__ void trans_load(const float* __restrict__ src,
                                           unsigned c0, unsigned hw0, int tid,
                                           f4 (&va)[4], f4 (&vb)[4]) {
#pragma unroll
  for (int j = 0; j < 4; ++j) {
    int idx = j * 256 + tid;
    int rp = idx >> 5;
    int q = idx & 31;
    const f4* base = (const f4*)(src + (size_t)(c0 + 2 * rp) * 65536u + hw0 + 4 * q);
    va[j] = __builtin_nontemporal_load(base);
    vb[j] = __builtin_nontemporal_load(base + 16384);
  }
}

__device__ __forceinline__ void trans_proc(unsigned* tile, __half* dst,
                                           unsigned c0, unsigned hw0, int tid,
                                           f4 (&va)[4], f4 (&vb)[4]) {
#pragma unroll
  for (int j = 0; j < 4; ++j) {
    int idx = j * 256 + tid;
    int rp = idx >> 5;
    int q = idx & 31;
#pragma unroll
    for (int k = 0; k < 4; ++k) {
      int hw = 4 * q + k;
      __half2 h = __floats2half2_rn(va[j][k], vb[j][k]);
      tile[hw * 36 + (rp ^ (hw >> 3))] = *(unsigned*)&h;
    }
  }
  __syncthreads();
  int seg = tid & 7;
#pragma unroll
  for (int jj = 0; jj < 4; ++jj) {
    int hw = jj * 32 + (tid >> 3);
    int s = hw >> 3;
    u4 v = *(const u4*)(tile + hw * 36 + 4 * ((seg ^ (s >> 2)) & 7));
    u4 o;
    switch (s & 3) {
      case 0: o = v; break;
      case 1: o = u4{v.y, v.x, v.w, v.z}; break;
      case 2: o = u4{v.z, v.w, v.x, v.y}; break;
      default: o = u4{v.w, v.z, v.y, v.x}; break;
    }
    *(u4*)((char*)dst + ((size_t)(hw0 + hw) * 256u + c0) * 2u + seg * 16u) = o;
  }
  __syncthreads();
}

// ---------------------------------------------------------------------------
// Sample body (R12-verified). FINAL=0: write fp16 partial[p]. FINAL=1
// (plane 2): add fp16 partials of planes 0,1 and write f32 out directly
// (fuses the old reduce pass; plane-2 term never rounds through fp16).
// ---------------------------------------------------------------------------
template <int FINAL>
__device__ __forceinline__ void samp_point(
    int p, int slot, int t, const unsigned* __restrict__ idx,
    const float* __restrict__ inputs, const __half* __restrict__ T,
    __half* __restrict__ partial, float* __restrict__ out) {
  unsigned n = idx[(size_t)p * NPTS + slot];
  float c0 = inputs[n * 3 + 0], c1 = inputs[n * 3 + 1], c2 = inputs[n * 3 + 2];
  float gx, gy, ax;
  plane_xy(p, c0, c1, c2, gx, gy, ax);

  float ix = (gx + 1.f) * 0.5f * 255.f;
  float iy = (gy + 1.f) * 0.5f * 255.f;
  float x0f = floorf(ix), y0f = floorf(iy);
  float wx = ix - x0f, wy = iy - y0f;
  int x0 = (int)x0f; x0 = x0 < 0 ? 0 : (x0 > 255 ? 255 : x0);
  int y0 = (int)y0f; y0 = y0 < 0 ? 0 : (y0 > 255 ? 255 : y0);
  int x1 = x0 + 1 > 255 ? 255 : x0 + 1;
  int y1 = y0 + 1 > 255 ? 255 : y0 + 1;
  float w00 = (1.f - wx) * (1.f - wy);
  float w01 = wx * (1.f - wy);
  float w10 = (1.f - wx) * wy;
  float w11 = wx * wy;

  const __half* __restrict__ P = T + (size_t)p * PLANE_ELEMS;
  int r00 = (y0 * 256 + x0) * 256, r01 = (y0 * 256 + x1) * 256;
  int r10 = (y1 * 256 + x0) * 256, r11 = (y1 * 256 + x1) * 256;
  int ore = t * 16;
  int oim = 128 + t * 16;

  f4 a0 = *(const f4*)(P + r00 + ore),     a1 = *(const f4*)(P + r00 + ore + 8);
  f4 a2 = *(const f4*)(P + r00 + oim),     a3 = *(const f4*)(P + r00 + oim + 8);
  f4 b0 = *(const f4*)(P + r01 + ore),     b1 = *(const f4*)(P + r01 + ore + 8);
  f4 b2 = *(const f4*)(P + r01 + oim),     b3 = *(const f4*)(P + r01 + oim + 8);
  f4 c0v = *(const f4*)(P + r10 + ore),    c1v = *(const f4*)(P + r10 + ore + 8);
  f4 c2v = *(const f4*)(P + r10 + oim),    c3v = *(const f4*)(P + r10 + oim + 8);
  f4 d0 = *(const f4*)(P + r11 + ore),     d1 = *(const f4*)(P + r11 + ore + 8);
  f4 d2 = *(const f4*)(P + r11 + oim),     d3 = *(const f4*)(P + r11 + oim + 8);

  __half2 hw00 = __float2half2_rn(w00), hw01 = __float2half2_rn(w01);
  __half2 hw10 = __float2half2_rn(w10), hw11 = __float2half2_rn(w11);

  __half2 bre[8], bim[8];
#pragma unroll
  for (int q = 0; q < 4; ++q) {
    __half2 v;
    v = __hmul2(((const __half2*)&a0)[q], hw00);
    v = __hfma2(((const __half2*)&b0)[q],  hw01, v);
    v = __hfma2(((const __half2*)&c0v)[q], hw10, v);
    bre[q] = __hfma2(((const __half2*)&d0)[q], hw11, v);

    v = __hmul2(((const __half2*)&a1)[q], hw00);
    v = __hfma2(((const __half2*)&b1)[q],  hw01, v);
    v = __hfma2(((const __half2*)&c1v)[q], hw10, v);
    bre[q + 4] = __hfma2(((const __half2*)&d1)[q], hw11, v);

    v = __hmul2(((const __half2*)&a2)[q], hw00);
    v = __hfma2(((const __half2*)&b2)[q],  hw01, v);
    v = __hfma2(((const __half2*)&c2v)[q], hw10, v);
    bim[q] = __hfma2(((const __half2*)&d2)[q], hw11, v);

    v = __hmul2(((const __half2*)&a3)[q], hw00);
    v = __hfma2(((const __half2*)&b3)[q],  hw01, v);
    v = __hfma2(((const __half2*)&c3v)[q], hw10, v);
    bim[q + 4] = __hfma2(((const __half2*)&d3)[q], hw11, v);
  }

  float fre[16], fim[16];
#pragma unroll
  for (int q = 0; q < 8; ++q) {
    float2 vr = __half22float2(bre[q]);
    float2 vi = __half22float2(bim[q]);
    fre[2 * q] = vr.x; fre[2 * q + 1] = vr.y;
    fim[2 * q] = vi.x; fim[2 * q + 1] = vi.y;
  }

  float cs = (ax + 1.f) * 0.5f * 255.f;
  float th = 6.283185307179586f * cs * (1.f / 256.f);
  float s, c;
  __sincosf(th, &s, &c);
  float aR0 = fre[0], aR1 = fre[8];
  float aI0 = 0.f,    aI1 = 0.f;
#pragma unroll
  for (int r = 1; r < 8; ++r) {
    aR0 += fre[r] * c;     aR1 += fre[8 + r] * c;
    aI0 += fim[r] * s;     aI1 += fim[8 + r] * s;
    if (r < 7) {
      float c2 = c + c;
      float cn = c2 * c - 1.f;
      s = c2 * s;
      c = cn;
    }
  }

  if (FINAL) {
    // fused reduce: add planes 0,1 partials, write f32 out (64B line/point)
    const size_t PS = (size_t)NPTS * 16;
    float2 p0 = __half22float2(*(const __half2*)(partial + (size_t)n * 16 + 2 * t));
    float2 p1 = __half22float2(*(const __half2*)(partial + PS + (size_t)n * 16 + 2 * t));
    float2 o;
    o.x = (aR0 - aI0) + p0.x + p1.x;
    o.y = (aR1 - aI1) + p0.y + p1.y;
    *(float2*)(out + (size_t)n * 16 + 2 * t) = o;
  } else {
    *(__half2*)(partial + ((size_t)p * NPTS + n) * 16 + 2 * t) =
        __floats2half2_rn(aR0 - aI0, aR1 - aI1);
  }
}

__device__ __forceinline__ void scat_point(
    int p, int n, const float* __restrict__ inputs,
    unsigned* __restrict__ hist, unsigned* __restrict__ idx) {
  float c0 = inputs[n * 3 + 0], c1 = inputs[n * 3 + 1], c2 = inputs[n * 3 + 2];
  float gx, gy, ax;
  plane_xy(p, c0, c1, c2, gx, gy, ax);
  int key = (cell_of(gy) << 8) | cell_of(gx);
  unsigned pos = atomicAdd(&hist[p * 65536 + key], 1u);
  idx[(size_t)p * NPTS + pos] = (unsigned)n;
}

// ---------------------------------------------------------------------------
// K1 fat kernel: trans ∥ hist, hist blocks interleaved (bx%3==2). [R14]
// grid 2304, block 256.
// ---------------------------------------------------------------------------
__global__ __launch_bounds__(256) void PREFFFT_fat1_k(
    const float* __restrict__ Pu, const float* __restrict__ Pv,
    const float* __restrict__ Pw, __half* __restrict__ dst0,
    const float* __restrict__ inputs, unsigned* __restrict__ hist) {
  __shared__ unsigned tile[128 * 36];
  const int bx = blockIdx.x;
  const int tid = threadIdx.x;
  if ((bx % 3) != 2) {
    int ti = (bx / 3) * 2 + (bx % 3);   // 0..1535
    int bz = ti / 512;
    int rem = ti - bz * 512;
    int by = rem >> 7;
    int bxx = rem & 127;
    const float* src = bz == 0 ? Pu : (bz == 1 ? Pv : Pw);
    __half* dst = dst0 + (size_t)bz * PLANE_ELEMS;
    const unsigned hwbase = bxx * 512u;
    const unsigned c0 = by * 64u;
    f4 vaA[4], vbA[4], vaB[4], vbB[4];
    trans_load(src, c0, hwbase, tid, vaA, vbA);
    trans_load(src, c0, hwbase + 128u, tid, vaB, vbB);
    trans_proc(tile, dst, c0, hwbase, tid, vaA, vbA);
    trans_load(src, c0, hwbase + 256u, tid, vaA, vbA);
    trans_proc(tile, dst, c0, hwbase + 128u, tid, vaB, vbB);
    trans_load(src, c0, hwbase + 384u, tid, vaB, vbB);
    trans_proc(tile, dst, c0, hwbase + 256u, tid, vaA, vbA);
    trans_proc(tile, dst, c0, hwbase + 384u, tid, vaB, vbB);
  } else {
    int hb = bx / 3;                    // 0..767
#pragma unroll
    for (int it = 0; it < 4; ++it) {
      int item = hb * 1024 + it * 256 + tid;
      int n = item & (NPTS - 1);
      int p = item >> 18;
      float c0 = inputs[n * 3 + 0], c1 = inputs[n * 3 + 1], c2 = inputs[n * 3 + 2];
      float gx, gy, ax;
      plane_xy(p, c0, c1, c2, gx, gy, ax);
      int key = (cell_of(gy) << 8) | cell_of(gx);
      atomicAdd(&hist[p * 65536 + key], 1u);
    }
  }
}

// ---------------------------------------------------------------------------
// Scan: exclusive prefix over 65536 bins; one block per plane.
// ---------------------------------------------------------------------------
__global__ __launch_bounds__(1024) void PREFFFT_scan_k(unsigned* __restrict__ hist) {
  __shared__ unsigned part[1024];
  unsigned* h = hist + (size_t)blockIdx.x * 65536;
  int t = threadIdx.x;
  unsigned s = 0;
#pragma unroll 8
  for (int i = 0; i < 64; ++i) s += h[t * 64 + i];
  part[t] = s;
  __syncthreads();
  for (int off = 1; off < 1024; off <<= 1) {
    unsigned v = (t >= off) ? part[t - off] : 0u;
    __syncthreads();
    part[t] += v;
    __syncthreads();
  }
  unsigned run = (t == 0) ? 0u : part[t - 1];
#pragma unroll 8
  for (int i = 0; i < 64; ++i) {
    unsigned c = h[t * 64 + i];
    h[t * 64 + i] = run;
    run += c;
  }
}

// ---------------------------------------------------------------------------
// Standalone scatter for plane 0 (the only latency-exposed one).
// ---------------------------------------------------------------------------
__global__ __launch_bounds__(256) void PREFFFT_scat1_k(
    const float* __restrict__ inputs, unsigned* __restrict__ hist,
    unsigned* __restrict__ idx) {
  int n = blockIdx.x * 256 + threadIdx.x;
  scat_point(0, n, inputs, hist, idx);
}

// ---------------------------------------------------------------------------
// Fat pipeline kernel: blocks [0,1024) = scat(plane sp+1) — dispatched first,
// latency hides under the 8192 samp(plane sp) blocks [1024, 9216).
// ---------------------------------------------------------------------------
__global__ __launch_bounds__(256) void PREFFFT_fat2_k(
    unsigned* __restrict__ idx, const float* __restrict__ inputs,
    const __half* __restrict__ T, __half* __restrict__ partial,
    unsigned* __restrict__ hist, int sp) {
  int bx = blockIdx.x;
  if (bx < 1024) {
    int n = bx * 256 + threadIdx.x;
    scat_point(sp + 1, n, inputs, hist, idx);
  } else {
    int b = bx - 1024;                        // 0..8191
    int lbx = (b & 7) * 1024 + (b >> 3);      // XCD-contiguous chunks
    int slot = lbx * 32 + ((int)threadIdx.x >> 3);
    samp_point<0>(sp, slot, threadIdx.x & 7, idx, inputs, T, partial, nullptr);
  }
}

// ---------------------------------------------------------------------------
// Final fused pass: samp(plane 2) + reduce(partials 0,1) -> f32 out. grid 8192.
// ---------------------------------------------------------------------------
__global__ __launch_bounds__(256) void PREFFFT_samp2out_k(
    const unsigned* __restrict__ idx, const float* __restrict__ inputs,
    const __half* __restrict__ T, __half* __restrict__ partial,
    float* __restrict__ out) {
  int b = blockIdx.x;
  int lbx = (b & 7) * 1024 + (b >> 3);
  int slot = lbx * 32 + ((int)threadIdx.x >> 3);
  samp_point<1>(2, slot, threadIdx.x & 7, idx, inputs, T, partial, out);
}

// ---------------------------------------------------------------------------
// Fallback (ws too small): original (C,H,W) fp32 direct, slow but correct.
// ---------------------------------------------------------------------------
__global__ __launch_bounds__(256) void PREFFFT_fallback_k(
    const float* __restrict__ inputs, const float* __restrict__ Tu,
    const float* __restrict__ Tv, const float* __restrict__ Tw,
    float* __restrict__ out) {
  int gtid = blockIdx.x * 256 + threadIdx.x;
  int n = gtid >> 5;
  int t = threadIdx.x & 31;
  const bool is_re = t < 16;
  float c0 = inputs[n * 3 + 0], c1 = inputs[n * 3 + 1], c2 = inputs[n * 3 + 2];
  const float* PL[3] = {Tu, Tv, Tw};
  float acc = 0.f;
#pragma unroll
  for (int p = 0; p < 3; ++p) {
    float gx, gy, ax;
    plane_xy(p, c0, c1, c2, gx, gy, ax);
    float ix = (gx + 1.f) * 0.5f * 255.f;
    float iy = (gy + 1.f) * 0.5f * 255.f;
    float x0f = floorf(ix), y0f = floorf(iy);
    float wx = ix - x0f, wy = iy - y0f;
    int x0 = (int)x0f; x0 = x0 < 0 ? 0 : (x0 > 255 ? 255 : x0);
    int y0 = (int)y0f; y0 = y0 < 0 ? 0 : (y0 > 255 ? 255 : y0);
    int x1 = x0 + 1 > 255 ? 255 : x0 + 1;
    int y1 = y0 + 1 > 255 ? 255 : y0 + 1;
    float w00 = (1.f - wx) * (1.f - wy), w01 = wx * (1.f - wy);
    float w10 = (1.f - wx) * wy, w11 = wx * wy;
    int i00 = y0 * 256 + x0, i01 = y0 * 256 + x1;
    int i10 = y1 * 256 + x0, i11 = y1 * 256 + x1;
    float b[8];
#pragma unroll
    for (int j = 0; j < 8; ++j) {
      const float* base = PL[p] + (size_t)(t * 8 + j) * 65536u;
      b[j] = w00 * base[i00] + w01 * base[i01] + w10 * base[i10] + w11 * base[i11];
    }
    float csv = (ax + 1.f) * 0.5f * 255.f;
    float theta1 = 6.283185307179586f * csv * (1.f / 256.f);
    float partial = is_re ? b[0] : 0.f;
#pragma unroll
    for (int r = 1; r < 8; ++r) {
      float thr = theta1 * (float)(1 << (r - 1));
      float s, c;
      __sincosf(thr, &s, &c);
      partial += b[r] * (is_re ? c : s);
    }
    float other = __shfl_xor(partial, 16);
    acc += partial - other;
  }
  if (is_re) out[n * 16 + t] = acc;
}

extern "C" void kernel_launch(void* const* d_in, const int* in_sizes, int n_in,
                              void* d_out, int out_size, void* d_ws, size_t ws_size,
                              hipStream_t stream) {
  const float* inputs = (const float*)d_in[0];
  const float* Pu = (const float*)d_in[1];
  const float* Pv = (const float*)d_in[2];
  const float* Pw = (const float*)d_in[3];
  float* out = (float*)d_out;

  if (ws_size >= WS_NEED) {
    char* ws = (char*)d_ws;
    __half*   T       = (__half*)ws;
    unsigned* idx     = (unsigned*)(ws + OFF_IDX);
    __half*   partial = (__half*)(ws + OFF_PARTIAL);
    unsigned* hist    = (unsigned*)(ws + OFF_HIST);

    hipMemsetAsync(hist, 0, (size_t)3 * 65536 * 4, stream);
    PREFFFT_fat1_k<<<2304, 256, 0, stream>>>(Pu, Pv, Pw, T, inputs, hist);
    PREFFFT_scan_k<<<3, 1024, 0, stream>>>(hist);
    PREFFFT_scat1_k<<<1024, 256, 0, stream>>>(inputs, hist, idx);
    PREFFFT_fat2_k<<<9216, 256, 0, stream>>>(idx, inputs, T, partial, hist, 0);
    PREFFFT_fat2_k<<<9216, 256, 0, stream>>>(idx, inputs, T, partial, hist, 1);
    PREFFFT_samp2out_k<<<8192, 256, 0, stream>>>(idx, inputs, T, partial, out);
  } else {
    PREFFFT_fallback_k<<<NPTS / 8, 256, 0, stream>>>(inputs, Pu, Pv, Pw, out);
  }
}